// Round 2
// baseline (3664.280 us; speedup 1.0000x reference)
//
#include <hip/hip_runtime.h>

#define SEQ 2048
#define BATCH 2
#define NH 16
#define DM 1024
#define DEPTH 64
#define MROWS (BATCH * SEQ)   // 4096

// ---------------- fp32 GEMM + bias: C[M,1024] = A[M,1024] @ W[1024,1024] + bias ----------------
#define BM 128
#define BN 64
#define BK 16

__global__ __launch_bounds__(256) void gemm_bias_kernel(const float* __restrict__ A,
                                                        const float* __restrict__ W,
                                                        const float* __restrict__ bias,
                                                        float* __restrict__ C) {
    __shared__ float As[BK][BM + 1];   // [16][129] — pad kills store bank conflicts
    __shared__ float Bs[BK][BN];       // [16][64]

    const int t  = threadIdx.x;
    const int tx = t & 15;    // col group: cols tx*4 .. tx*4+3
    const int ty = t >> 4;    // row group: rows i*16+ty, i=0..7
    const int row0 = blockIdx.y * BM;
    const int col0 = blockIdx.x * BN;

    float acc[8][4];
#pragma unroll
    for (int i = 0; i < 8; ++i)
#pragma unroll
        for (int j = 0; j < 4; ++j) acc[i][j] = 0.f;

    const int arow = t >> 2;          // 0..63
    const int akg  = (t & 3) * 4;     // 0,4,8,12
    const int bkk  = t >> 4;          // 0..15
    const int bcol = (t & 15) * 4;    // 0..60

    for (int k0 = 0; k0 < DM; k0 += BK) {
#pragma unroll
        for (int half = 0; half < 2; ++half) {
            const int row = arow + half * 64;
            const float4 v = *(const float4*)&A[(size_t)(row0 + row) * DM + k0 + akg];
            As[akg + 0][row] = v.x;
            As[akg + 1][row] = v.y;
            As[akg + 2][row] = v.z;
            As[akg + 3][row] = v.w;
        }
        {
            const float4 w = *(const float4*)&W[(size_t)(k0 + bkk) * DM + col0 + bcol];
            *(float4*)&Bs[bkk][bcol] = w;
        }
        __syncthreads();
#pragma unroll
        for (int kk = 0; kk < BK; ++kk) {
            const float4 b4 = *(const float4*)&Bs[kk][tx * 4];
#pragma unroll
            for (int i = 0; i < 8; ++i) {
                const float a = As[kk][i * 16 + ty];
                acc[i][0] += a * b4.x;
                acc[i][1] += a * b4.y;
                acc[i][2] += a * b4.z;
                acc[i][3] += a * b4.w;
            }
        }
        __syncthreads();
    }

    const float4 bi = *(const float4*)&bias[col0 + tx * 4];
#pragma unroll
    for (int i = 0; i < 8; ++i) {
        const int row = row0 + i * 16 + ty;
        float4 o;
        o.x = acc[i][0] + bi.x;
        o.y = acc[i][1] + bi.y;
        o.z = acc[i][2] + bi.z;
        o.w = acc[i][3] + bi.w;
        *(float4*)&C[(size_t)row * DM + col0 + tx * 4] = o;
    }
}

// ---------------- fused attention v2: wave-parallel softmax, chunked PV ----------------
// One block = QB=8 query rows of one (b,h). 256 threads (4 waves).
// Thread t owns key j = i*256 + t for i=0..7 (all 2048 keys x 8 rows in regs).
#define QB 8

__global__ __launch_bounds__(256, 4) void attn_kernel(const float* __restrict__ Qb,
                                                      const float* __restrict__ Kb,
                                                      const float* __restrict__ Vb,
                                                      float* __restrict__ attn_out,
                                                      float* __restrict__ Ctx) {
    // LDS layout (floats):
    //   pl  [0 .. 2047]      : p chunk [QB][256]  (later reused as ctx partials [4][QB][64])
    //   qs  [2048 .. 2559]   : q rows [QB][64]
    //   redm[2560 .. 2591]   : per-wave max  [4][QB]
    //   reds[2592 .. 2623]   : per-wave sum  [4][QB]
    __shared__ float smem[2624];   // 10.25 KB
    float* pl   = smem;
    float* qs   = smem + 2048;
    float* redm = smem + 2560;
    float* reds = smem + 2592;

    const int t    = threadIdx.x;
    const int lane = t & 63;
    const int w    = t >> 6;                     // wave id 0..3
    const int qb   = blockIdx.x & (SEQ / QB - 1);
    const int bh   = blockIdx.x >> 8;            // 0..31
    const int b    = bh >> 4;
    const int h    = bh & 15;
    const int q0   = qb * QB;

    const size_t panel = (size_t)b * SEQ * DM + (size_t)h * DEPTH;

    // phase 0: load q rows, pre-scaled by 1/sqrt(64)
    for (int idx = t; idx < QB * DEPTH; idx += 256) {
        const int r = idx >> 6, d = idx & 63;
        qs[r * DEPTH + d] = Qb[panel + (size_t)(q0 + r) * DM + d] * 0.125f;
    }
    __syncthreads();

    // phase 1: logits. acc[i][r] = logit(row q0+r, key i*256+t)
    float acc[8][QB];
#pragma unroll
    for (int i = 0; i < 8; ++i)
#pragma unroll
        for (int r = 0; r < QB; ++r) acc[i][r] = 0.f;

    const float* Kp = Kb + panel + (size_t)t * DM;
#pragma unroll 4
    for (int dd = 0; dd < DEPTH; dd += 4) {
        float4 q4[QB];
#pragma unroll
        for (int r = 0; r < QB; ++r) q4[r] = *(const float4*)&qs[r * DEPTH + dd];
#pragma unroll
        for (int i = 0; i < 8; ++i) {
            const float4 kv = *(const float4*)&Kp[(size_t)i * 256 * DM + dd];
#pragma unroll
            for (int r = 0; r < QB; ++r) {
                acc[i][r] += kv.x * q4[r].x + kv.y * q4[r].y + kv.z * q4[r].z + kv.w * q4[r].w;
            }
        }
    }

    // phase 2a: row max — shuffle reduce within wave, LDS combine across 4 waves
#pragma unroll
    for (int r = 0; r < QB; ++r) {
        float m = acc[0][r];
#pragma unroll
        for (int i = 1; i < 8; ++i) m = fmaxf(m, acc[i][r]);
#pragma unroll
        for (int off = 1; off < 64; off <<= 1) m = fmaxf(m, __shfl_xor(m, off));
        if (lane == 0) redm[w * QB + r] = m;
    }
    __syncthreads();

    float mx[QB];
#pragma unroll
    for (int r = 0; r < QB; ++r) {
        mx[r] = fmaxf(fmaxf(redm[0 * QB + r], redm[1 * QB + r]),
                      fmaxf(redm[2 * QB + r], redm[3 * QB + r]));
    }

    // phase 2b: exp in place + row sum
#pragma unroll
    for (int r = 0; r < QB; ++r) {
        float s = 0.f;
#pragma unroll
        for (int i = 0; i < 8; ++i) {
            const float p = __expf(acc[i][r] - mx[r]);
            acc[i][r] = p;
            s += p;
        }
#pragma unroll
        for (int off = 1; off < 64; off <<= 1) s += __shfl_xor(s, off);
        if (lane == 0) reds[w * QB + r] = s;
    }
    __syncthreads();

    float rinv[QB];
#pragma unroll
    for (int r = 0; r < QB; ++r) {
        rinv[r] = 1.f / (reds[0 * QB + r] + reds[1 * QB + r] + reds[2 * QB + r] + reds[3 * QB + r]);
    }

    // phase 3: chunked attn write + PV
    const int d4 = (t & 15) * 4;
    const int g  = t >> 4;                       // 0..15 (wave w covers g = 4w..4w+3)
    const float* Vp = Vb + panel;
    float* attn_base = attn_out + ((size_t)bh * SEQ + q0) * SEQ;

    float4 cacc[QB];
#pragma unroll
    for (int r = 0; r < QB; ++r) cacc[r] = make_float4(0.f, 0.f, 0.f, 0.f);

    for (int i = 0; i < 8; ++i) {
#pragma unroll
        for (int r = 0; r < QB; ++r) {
            const float p = acc[i][r] * rinv[r];
            pl[r * 256 + t] = p;
            attn_base[(size_t)r * SEQ + i * 256 + t] = p;
        }
        __syncthreads();
#pragma unroll
        for (int jj = 0; jj < 16; ++jj) {
            const int j = jj * 16 + g;
            const float4 vv = *(const float4*)&Vp[(size_t)(i * 256 + j) * DM + d4];
#pragma unroll
            for (int r = 0; r < QB; ++r) {
                const float p = pl[r * 256 + j];
                cacc[r].x += p * vv.x;
                cacc[r].y += p * vv.y;
                cacc[r].z += p * vv.z;
                cacc[r].w += p * vv.w;
            }
        }
        __syncthreads();
    }

    // phase 4: reduce ctx over the 4 g-values within each wave (lanes l, l^16, l^32, l^48
    // share d4), then across the 4 waves via LDS.
#pragma unroll
    for (int r = 0; r < QB; ++r) {
#pragma unroll
        for (int off = 16; off < 64; off <<= 1) {
            cacc[r].x += __shfl_xor(cacc[r].x, off);
            cacc[r].y += __shfl_xor(cacc[r].y, off);
            cacc[r].z += __shfl_xor(cacc[r].z, off);
            cacc[r].w += __shfl_xor(cacc[r].w, off);
        }
    }
    if (lane < 16) {
#pragma unroll
        for (int r = 0; r < QB; ++r) {
            *(float4*)&pl[((size_t)w * QB + r) * DEPTH + lane * 4] = cacc[r];
        }
    }
    __syncthreads();

    for (int idx = t; idx < QB * DEPTH; idx += 256) {
        const int r = idx >> 6, d = idx & 63;
        const float s = pl[(0 * QB + r) * DEPTH + d] + pl[(1 * QB + r) * DEPTH + d] +
                        pl[(2 * QB + r) * DEPTH + d] + pl[(3 * QB + r) * DEPTH + d];
        Ctx[panel + (size_t)(q0 + r) * DM + d] = s;
    }
}

extern "C" void kernel_launch(void* const* d_in, const int* in_sizes, int n_in,
                              void* d_out, int out_size, void* d_ws, size_t ws_size,
                              hipStream_t stream) {
    const float* x  = (const float*)d_in[0];
    const float* wq = (const float*)d_in[1];
    const float* bq = (const float*)d_in[2];
    const float* wk = (const float*)d_in[3];
    const float* bk = (const float*)d_in[4];
    const float* wv = (const float*)d_in[5];
    const float* bv = (const float*)d_in[6];
    const float* wo = (const float*)d_in[7];
    const float* bo = (const float*)d_in[8];

    float* out  = (float*)d_out;                          // [2,2048,1024]
    float* attn = out + (size_t)MROWS * DM;               // [2,16,2048,2048]

    float* ws = (float*)d_ws;
    float* Qb = ws;
    float* Kb = Qb + (size_t)MROWS * DM;
    float* Vb = Kb + (size_t)MROWS * DM;
    float* Cx = Vb + (size_t)MROWS * DM;

    const dim3 gblk(DM / BN, MROWS / BM);   // (16, 32)
    gemm_bias_kernel<<<gblk, 256, 0, stream>>>(x, wq, bq, Qb);
    gemm_bias_kernel<<<gblk, 256, 0, stream>>>(x, wk, bk, Kb);
    gemm_bias_kernel<<<gblk, 256, 0, stream>>>(x, wv, bv, Vb);

    attn_kernel<<<dim3(BATCH * NH * SEQ / QB), 256, 0, stream>>>(Qb, Kb, Vb, attn, Cx);

    gemm_bias_kernel<<<gblk, 256, 0, stream>>>(Cx, wo, bo, out);
}

// Round 3
// 1306.233 us; speedup vs baseline: 2.8052x; 2.8052x over previous
//
#include <hip/hip_runtime.h>
#include <hip/hip_bf16.h>

#define SEQ 2048
#define BATCH 2
#define NH 16
#define DM 1024
#define DEPTH 64
#define MROWS (BATCH * SEQ)   // 4096
#define QB 8

typedef __attribute__((ext_vector_type(8))) short bf16x8;
typedef __attribute__((ext_vector_type(4))) float f32x4;

__device__ __forceinline__ float b2f(ushort u) {
    union { uint i; float f; } v; v.i = ((uint)u) << 16; return v.f;
}
__device__ __forceinline__ ushort f2b(float f) {
    __hip_bfloat16 h = __float2bfloat16(f);
    return *reinterpret_cast<ushort*>(&h);
}

__device__ __forceinline__ void gload_lds16(const void* g, void* l) {
    __builtin_amdgcn_global_load_lds((const __attribute__((address_space(1))) void*)g,
                                     (__attribute__((address_space(3))) void*)l, 16, 0, 0);
}

// ---------------- fp32 -> bf16 elementwise (x, 4 elems/thread) ----------------
__global__ __launch_bounds__(256) void convert_f32_bf16(const float* __restrict__ in,
                                                        ushort* __restrict__ outp, int n4) {
    int i = blockIdx.x * 256 + threadIdx.x;
    if (i < n4) {
        const float4 v = ((const float4*)in)[i];
        ushort4 o;
        o.x = f2b(v.x); o.y = f2b(v.y); o.z = f2b(v.z); o.w = f2b(v.w);
        ((ushort4*)outp)[i] = o;
    }
}

// ---------------- fp32 W[K][N] -> bf16 Wt[N][K] (tiled transpose) ----------------
__global__ __launch_bounds__(256) void transpose_convert(const float* __restrict__ W,
                                                         ushort* __restrict__ Wt) {
    __shared__ float tile[32][33];
    const int bx = blockIdx.x * 32;  // n base
    const int by = blockIdx.y * 32;  // k base
    const int tx = threadIdx.x & 31, ty = threadIdx.x >> 5;  // ty 0..7
#pragma unroll
    for (int i = 0; i < 32; i += 8)
        tile[ty + i][tx] = W[(size_t)(by + ty + i) * DM + bx + tx];
    __syncthreads();
#pragma unroll
    for (int i = 0; i < 32; i += 8)
        Wt[(size_t)(bx + ty + i) * DM + by + tx] = f2b(tile[tx][ty + i]);
}

// ---------------- bf16 MFMA GEMM: C[M,1024] = A[M,1024] @ Wt^T + bias ----------------
// A: bf16 [M][1024] row-major. Wt: bf16 [1024 n][1024 k] (pre-transposed).
// 128x128 tile, 4 waves in 2x2, each wave 64x64 via 4x4 mfma_f32_16x16x32_bf16 frags.
template <bool BF16OUT>
__global__ __launch_bounds__(256) void gemm_mfma(const ushort* __restrict__ A,
                                                 const ushort* __restrict__ Wt,
                                                 const float* __restrict__ bias,
                                                 void* __restrict__ Cout) {
    __shared__ __align__(16) ushort As[128 * 32];   // [row][k] 8 KB
    __shared__ __align__(16) ushort Bs[128 * 32];   // [n][k]   8 KB

    const int t    = threadIdx.x;
    const int lane = t & 63;
    const int w    = t >> 6;
    const int wr   = w >> 1, wc = w & 1;
    const int row0 = blockIdx.y * 128;
    const int col0 = blockIdx.x * 128;

    f32x4 acc[4][4];
#pragma unroll
    for (int mi = 0; mi < 4; ++mi)
#pragma unroll
        for (int ni = 0; ni < 4; ++ni) acc[mi][ni] = (f32x4){0.f, 0.f, 0.f, 0.f};

    const int sr = t >> 2;         // 0..63
    const int sc = (t & 3) * 8;    // 0,8,16,24

    for (int k0 = 0; k0 < DM; k0 += 32) {
        // stage A[128][32]: thread t <-> LDS bytes t*16 (+4096 for second half)
        gload_lds16(&A[(size_t)(row0 + sr) * DM + k0 + sc],       &As[w * 512]);
        gload_lds16(&A[(size_t)(row0 + 64 + sr) * DM + k0 + sc],  &As[2048 + w * 512]);
        gload_lds16(&Wt[(size_t)(col0 + sr) * DM + k0 + sc],      &Bs[w * 512]);
        gload_lds16(&Wt[(size_t)(col0 + 64 + sr) * DM + k0 + sc], &Bs[2048 + w * 512]);
        __syncthreads();   // drains vmcnt before barrier

        bf16x8 af[4], bfr[4];
#pragma unroll
        for (int mi = 0; mi < 4; ++mi)
            af[mi] = *(const bf16x8*)&As[(wr * 64 + mi * 16 + (lane & 15)) * 32 + (lane >> 4) * 8];
#pragma unroll
        for (int ni = 0; ni < 4; ++ni)
            bfr[ni] = *(const bf16x8*)&Bs[(wc * 64 + ni * 16 + (lane & 15)) * 32 + (lane >> 4) * 8];
#pragma unroll
        for (int mi = 0; mi < 4; ++mi)
#pragma unroll
            for (int ni = 0; ni < 4; ++ni)
                acc[mi][ni] = __builtin_amdgcn_mfma_f32_16x16x32_bf16(af[mi], bfr[ni], acc[mi][ni], 0, 0, 0);
        __syncthreads();
    }

    float bb[4];
#pragma unroll
    for (int ni = 0; ni < 4; ++ni) bb[ni] = bias[col0 + wc * 64 + ni * 16 + (lane & 15)];

#pragma unroll
    for (int mi = 0; mi < 4; ++mi) {
        const int row = row0 + wr * 64 + mi * 16 + (lane >> 4) * 4;
#pragma unroll
        for (int ni = 0; ni < 4; ++ni) {
            const int col = col0 + wc * 64 + ni * 16 + (lane & 15);
#pragma unroll
            for (int r = 0; r < 4; ++r) {
                const float v = acc[mi][ni][r] + bb[ni];
                if (BF16OUT)
                    ((ushort*)Cout)[(size_t)(row + r) * DM + col] = f2b(v);
                else
                    ((float*)Cout)[(size_t)(row + r) * DM + col] = v;
            }
        }
    }
}

// ---------------- fused attention v3: bf16 Q/K/V in, fp32 softmax, bf16 ctx out ----------------
__global__ __launch_bounds__(256) void attn_kernel(const ushort* __restrict__ Qh,
                                                   const ushort* __restrict__ Kh,
                                                   const ushort* __restrict__ Vh,
                                                   float* __restrict__ attn_out,
                                                   ushort* __restrict__ Ctx) {
    __shared__ __align__(16) float smem[2624];   // pl[2048] | qs[512] | redm[32] | reds[32]
    float* pl   = smem;
    float* qs   = smem + 2048;
    float* redm = smem + 2560;
    float* reds = smem + 2592;

    const int t    = threadIdx.x;
    const int lane = t & 63;
    const int w    = t >> 6;
    const int qb   = blockIdx.x & (SEQ / QB - 1);
    const int bh   = blockIdx.x >> 8;
    const int b    = bh >> 4;
    const int h    = bh & 15;
    const int q0   = qb * QB;

    const size_t panel = (size_t)b * SEQ * DM + (size_t)h * DEPTH;

    for (int idx = t; idx < QB * DEPTH; idx += 256) {
        const int r = idx >> 6, d = idx & 63;
        qs[r * DEPTH + d] = b2f(Qh[panel + (size_t)(q0 + r) * DM + d]) * 0.125f;
    }
    __syncthreads();

    float acc[8][QB];
#pragma unroll
    for (int i = 0; i < 8; ++i)
#pragma unroll
        for (int r = 0; r < QB; ++r) acc[i][r] = 0.f;

    const ushort* Kp = Kh + panel + (size_t)t * DM;
#pragma unroll 4
    for (int dd = 0; dd < DEPTH; dd += 4) {
        float4 q4[QB];
#pragma unroll
        for (int r = 0; r < QB; ++r) q4[r] = *(const float4*)&qs[r * DEPTH + dd];
#pragma unroll
        for (int i = 0; i < 8; ++i) {
            const ushort4 ku = *(const ushort4*)&Kp[(size_t)i * 256 * DM + dd];
            const float kx = b2f(ku.x), ky = b2f(ku.y), kz = b2f(ku.z), kw = b2f(ku.w);
#pragma unroll
            for (int r = 0; r < QB; ++r) {
                acc[i][r] += kx * q4[r].x + ky * q4[r].y + kz * q4[r].z + kw * q4[r].w;
            }
        }
    }

    // row max: wave shuffle + LDS combine
#pragma unroll
    for (int r = 0; r < QB; ++r) {
        float m = acc[0][r];
#pragma unroll
        for (int i = 1; i < 8; ++i) m = fmaxf(m, acc[i][r]);
#pragma unroll
        for (int off = 1; off < 64; off <<= 1) m = fmaxf(m, __shfl_xor(m, off));
        if (lane == 0) redm[w * QB + r] = m;
    }
    __syncthreads();

    float mx[QB];
#pragma unroll
    for (int r = 0; r < QB; ++r)
        mx[r] = fmaxf(fmaxf(redm[0 * QB + r], redm[1 * QB + r]),
                      fmaxf(redm[2 * QB + r], redm[3 * QB + r]));

    // exp in place + row sum
#pragma unroll
    for (int r = 0; r < QB; ++r) {
        float s = 0.f;
#pragma unroll
        for (int i = 0; i < 8; ++i) {
            const float p = __expf(acc[i][r] - mx[r]);
            acc[i][r] = p;
            s += p;
        }
#pragma unroll
        for (int off = 1; off < 64; off <<= 1) s += __shfl_xor(s, off);
        if (lane == 0) reds[w * QB + r] = s;
    }
    __syncthreads();

    float rinv[QB];
#pragma unroll
    for (int r = 0; r < QB; ++r)
        rinv[r] = 1.f / (reds[0 * QB + r] + reds[1 * QB + r] + reds[2 * QB + r] + reds[3 * QB + r]);

    // chunked attn write + PV
    const int d4 = (t & 15) * 4;
    const int g  = t >> 4;
    const ushort* Vp = Vh + panel;
    float* attn_base = attn_out + ((size_t)bh * SEQ + q0) * SEQ;

    float4 cacc[QB];
#pragma unroll
    for (int r = 0; r < QB; ++r) cacc[r] = make_float4(0.f, 0.f, 0.f, 0.f);

    for (int i = 0; i < 8; ++i) {
#pragma unroll
        for (int r = 0; r < QB; ++r) {
            const float p = acc[i][r] * rinv[r];
            pl[r * 256 + t] = p;
            attn_base[(size_t)r * SEQ + i * 256 + t] = p;
        }
        __syncthreads();
#pragma unroll
        for (int jj = 0; jj < 16; ++jj) {
            const int j = jj * 16 + g;
            const ushort4 vu = *(const ushort4*)&Vp[(size_t)(i * 256 + j) * DM + d4];
            const float vx = b2f(vu.x), vy = b2f(vu.y), vz = b2f(vu.z), vw = b2f(vu.w);
#pragma unroll
            for (int r = 0; r < QB; ++r) {
                const float p = pl[r * 256 + j];
                cacc[r].x += p * vx;
                cacc[r].y += p * vy;
                cacc[r].z += p * vz;
                cacc[r].w += p * vw;
            }
        }
        __syncthreads();
    }

    // reduce ctx over g within wave (lanes l, l^16, l^32, l^48 share d4), then across waves
#pragma unroll
    for (int r = 0; r < QB; ++r) {
#pragma unroll
        for (int off = 16; off < 64; off <<= 1) {
            cacc[r].x += __shfl_xor(cacc[r].x, off);
            cacc[r].y += __shfl_xor(cacc[r].y, off);
            cacc[r].z += __shfl_xor(cacc[r].z, off);
            cacc[r].w += __shfl_xor(cacc[r].w, off);
        }
    }
    if (lane < 16) {
#pragma unroll
        for (int r = 0; r < QB; ++r)
            *(float4*)&pl[((size_t)w * QB + r) * DEPTH + lane * 4] = cacc[r];
    }
    __syncthreads();

    for (int idx = t; idx < QB * DEPTH; idx += 256) {
        const int r = idx >> 6, d = idx & 63;
        const float s = pl[(0 * QB + r) * DEPTH + d] + pl[(1 * QB + r) * DEPTH + d] +
                        pl[(2 * QB + r) * DEPTH + d] + pl[(3 * QB + r) * DEPTH + d];
        Ctx[panel + (size_t)(q0 + r) * DM + d] = f2b(s);
    }
}

extern "C" void kernel_launch(void* const* d_in, const int* in_sizes, int n_in,
                              void* d_out, int out_size, void* d_ws, size_t ws_size,
                              hipStream_t stream) {
    const float* x  = (const float*)d_in[0];
    const float* wq = (const float*)d_in[1];
    const float* bq = (const float*)d_in[2];
    const float* wk = (const float*)d_in[3];
    const float* bk = (const float*)d_in[4];
    const float* wv = (const float*)d_in[5];
    const float* bv = (const float*)d_in[6];
    const float* wo = (const float*)d_in[7];
    const float* bo = (const float*)d_in[8];

    float* out  = (float*)d_out;                          // [2,2048,1024]
    float* attn = out + (size_t)MROWS * DM;               // [2,16,2048,2048]

    ushort* ws  = (ushort*)d_ws;
    ushort* xb  = ws;                       // 4096x1024
    ushort* wqt = xb + (size_t)MROWS * DM;  // 1024x1024 each, transposed [n][k]
    ushort* wkt = wqt + (size_t)DM * DM;
    ushort* wvt = wkt + (size_t)DM * DM;
    ushort* wot = wvt + (size_t)DM * DM;
    ushort* Qh  = wot + (size_t)DM * DM;    // 4096x1024 bf16
    ushort* Kh  = Qh + (size_t)MROWS * DM;
    ushort* Vh  = Kh + (size_t)MROWS * DM;
    ushort* cxb = Vh + (size_t)MROWS * DM;

    const dim3 tgrid(DM / 32, DM / 32);     // (32,32)
    convert_f32_bf16<<<dim3(MROWS * DM / 4 / 256), 256, 0, stream>>>(x, xb, MROWS * DM / 4);
    transpose_convert<<<tgrid, 256, 0, stream>>>(wq, wqt);
    transpose_convert<<<tgrid, 256, 0, stream>>>(wk, wkt);
    transpose_convert<<<tgrid, 256, 0, stream>>>(wv, wvt);
    transpose_convert<<<tgrid, 256, 0, stream>>>(wo, wot);

    const dim3 ggrid(DM / 128, MROWS / 128);  // (8,32)
    gemm_mfma<true><<<ggrid, 256, 0, stream>>>(xb, wqt, bq, Qh);
    gemm_mfma<true><<<ggrid, 256, 0, stream>>>(xb, wkt, bk, Kh);
    gemm_mfma<true><<<ggrid, 256, 0, stream>>>(xb, wvt, bv, Vh);

    attn_kernel<<<dim3(BATCH * NH * SEQ / QB), 256, 0, stream>>>(Qh, Kh, Vh, attn, cxb);

    gemm_mfma<false><<<ggrid, 256, 0, stream>>>(cxb, wot, bo, out);
}

// Round 4
// 520.372 us; speedup vs baseline: 7.0417x; 2.5102x over previous
//
#include <hip/hip_runtime.h>
#include <hip/hip_bf16.h>

#define SEQ 2048
#define BATCH 2
#define NH 16
#define DM 1024
#define DEPTH 64
#define MROWS (BATCH * SEQ)   // 4096

typedef __attribute__((ext_vector_type(8))) short bf16x8;
typedef __attribute__((ext_vector_type(4))) float f32x4;

__device__ __forceinline__ float b2f(ushort u) {
    union { uint i; float f; } v; v.i = ((uint)u) << 16; return v.f;
}
__device__ __forceinline__ ushort f2b(float f) {
    __hip_bfloat16 h = __float2bfloat16(f);
    return *reinterpret_cast<ushort*>(&h);
}

__device__ __forceinline__ void gload_lds16(const void* g, void* l) {
    __builtin_amdgcn_global_load_lds((const __attribute__((address_space(1))) void*)g,
                                     (__attribute__((address_space(3))) void*)l, 16, 0, 0);
}

// ---------------- fp32 -> bf16 elementwise ----------------
__global__ __launch_bounds__(256) void convert_f32_bf16(const float* __restrict__ in,
                                                        ushort* __restrict__ outp, int n4) {
    int i = blockIdx.x * 256 + threadIdx.x;
    if (i < n4) {
        const float4 v = ((const float4*)in)[i];
        ushort4 o;
        o.x = f2b(v.x); o.y = f2b(v.y); o.z = f2b(v.z); o.w = f2b(v.w);
        ((ushort4*)outp)[i] = o;
    }
}

// ---------------- fp32 W[K][N] -> bf16 Wt[N][K] ----------------
__global__ __launch_bounds__(256) void transpose_convert(const float* __restrict__ W,
                                                         ushort* __restrict__ Wt) {
    __shared__ float tile[32][33];
    const int bx = blockIdx.x * 32;  // n base
    const int by = blockIdx.y * 32;  // k base
    const int tx = threadIdx.x & 31, ty = threadIdx.x >> 5;
#pragma unroll
    for (int i = 0; i < 32; i += 8)
        tile[ty + i][tx] = W[(size_t)(by + ty + i) * DM + bx + tx];
    __syncthreads();
#pragma unroll
    for (int i = 0; i < 32; i += 8)
        Wt[(size_t)(bx + ty + i) * DM + by + tx] = f2b(tile[tx][ty + i]);
}

// ---------------- bf16 MFMA GEMM (verified R3): C = A @ Wt^T + bias ----------------
template <bool BF16OUT>
__global__ __launch_bounds__(256) void gemm_mfma(const ushort* __restrict__ A,
                                                 const ushort* __restrict__ Wt,
                                                 const float* __restrict__ bias,
                                                 void* __restrict__ Cout) {
    __shared__ __align__(16) ushort As[128 * 32];
    __shared__ __align__(16) ushort Bs[128 * 32];

    const int t    = threadIdx.x;
    const int lane = t & 63;
    const int w    = t >> 6;
    const int wr   = w >> 1, wc = w & 1;
    const int row0 = blockIdx.y * 128;
    const int col0 = blockIdx.x * 128;

    f32x4 acc[4][4];
#pragma unroll
    for (int mi = 0; mi < 4; ++mi)
#pragma unroll
        for (int ni = 0; ni < 4; ++ni) acc[mi][ni] = (f32x4){0.f, 0.f, 0.f, 0.f};

    const int sr = t >> 2;
    const int sc = (t & 3) * 8;

    for (int k0 = 0; k0 < DM; k0 += 32) {
        gload_lds16(&A[(size_t)(row0 + sr) * DM + k0 + sc],       &As[w * 512]);
        gload_lds16(&A[(size_t)(row0 + 64 + sr) * DM + k0 + sc],  &As[2048 + w * 512]);
        gload_lds16(&Wt[(size_t)(col0 + sr) * DM + k0 + sc],      &Bs[w * 512]);
        gload_lds16(&Wt[(size_t)(col0 + 64 + sr) * DM + k0 + sc], &Bs[2048 + w * 512]);
        __syncthreads();

        bf16x8 af[4], bfr[4];
#pragma unroll
        for (int mi = 0; mi < 4; ++mi)
            af[mi] = *(const bf16x8*)&As[(wr * 64 + mi * 16 + (lane & 15)) * 32 + (lane >> 4) * 8];
#pragma unroll
        for (int ni = 0; ni < 4; ++ni)
            bfr[ni] = *(const bf16x8*)&Bs[(wc * 64 + ni * 16 + (lane & 15)) * 32 + (lane >> 4) * 8];
#pragma unroll
        for (int mi = 0; mi < 4; ++mi)
#pragma unroll
            for (int ni = 0; ni < 4; ++ni)
                acc[mi][ni] = __builtin_amdgcn_mfma_f32_16x16x32_bf16(af[mi], bfr[ni], acc[mi][ni], 0, 0, 0);
        __syncthreads();
    }

    float bb[4];
#pragma unroll
    for (int ni = 0; ni < 4; ++ni) bb[ni] = bias[col0 + wc * 64 + ni * 16 + (lane & 15)];

#pragma unroll
    for (int mi = 0; mi < 4; ++mi) {
        const int row = row0 + wr * 64 + mi * 16 + (lane >> 4) * 4;
#pragma unroll
        for (int ni = 0; ni < 4; ++ni) {
            const int col = col0 + wc * 64 + ni * 16 + (lane & 15);
#pragma unroll
            for (int r = 0; r < 4; ++r) {
                const float v = acc[mi][ni][r] + bb[ni];
                if (BF16OUT)
                    ((ushort*)Cout)[(size_t)(row + r) * DM + col] = f2b(v);
                else
                    ((float*)Cout)[(size_t)(row + r) * DM + col] = v;
            }
        }
    }
}

// ---------------- QK^T (MFMA) + softmax + coalesced fp32 attn write ----------------
// Block: 512 threads (8 waves), one (b,h) x 16 q-rows. Wave w owns keys [w*256, w*256+256).
// Lane holds S[q=(lane>>4)*4+r][k=w*256+kt*16+(lane&15)] for kt=0..15 (64 fp32 regs).
__global__ __launch_bounds__(512) void qk_softmax_kernel(const ushort* __restrict__ Qh,
                                                         const ushort* __restrict__ Kh,
                                                         float* __restrict__ attn_out) {
    __shared__ float redm[8][16];
    __shared__ float reds[8][16];

    const int t    = threadIdx.x;
    const int lane = t & 63;
    const int w    = t >> 6;          // 0..7
    const int bh   = blockIdx.x;      // 0..31
    const int qt   = blockIdx.y;      // 0..127
    const int b    = bh >> 4;
    const int h    = bh & 15;
    const int q0   = qt * 16;

    const size_t panel = (size_t)b * SEQ * DM + (size_t)h * DEPTH;

    // Q fragments (A operand): lane holds Q[q0+(lane&15)][(lane>>4)*8 + ks*32 ..+7]
    const ushort* Qrow = Qh + panel + (size_t)(q0 + (lane & 15)) * DM + (lane >> 4) * 8;
    const bf16x8 qf0 = *(const bf16x8*)Qrow;
    const bf16x8 qf1 = *(const bf16x8*)(Qrow + 32);

    f32x4 acc[16];
#pragma unroll
    for (int kt = 0; kt < 16; ++kt) acc[kt] = (f32x4){0.f, 0.f, 0.f, 0.f};

    // K fragments (B operand) gathered from global: lane holds K[w*256+kt*16+(lane&15)][..]
    const ushort* Kbase = Kh + panel + (size_t)(w * 256) * DM + (lane >> 4) * 8;
#pragma unroll
    for (int kt = 0; kt < 16; ++kt) {
        const ushort* Kr = Kbase + (size_t)(kt * 16 + (lane & 15)) * DM;
        const bf16x8 kf0 = *(const bf16x8*)Kr;
        const bf16x8 kf1 = *(const bf16x8*)(Kr + 32);
        acc[kt] = __builtin_amdgcn_mfma_f32_16x16x32_bf16(qf0, kf0, acc[kt], 0, 0, 0);
        acc[kt] = __builtin_amdgcn_mfma_f32_16x16x32_bf16(qf1, kf1, acc[kt], 0, 0, 0);
    }

    // scale by 1/sqrt(64)
#pragma unroll
    for (int kt = 0; kt < 16; ++kt) {
        acc[kt][0] *= 0.125f; acc[kt][1] *= 0.125f;
        acc[kt][2] *= 0.125f; acc[kt][3] *= 0.125f;
    }

    // row max: per-lane over kt, then across the 16 lanes of the k-group, then across waves
    float m[4];
#pragma unroll
    for (int r = 0; r < 4; ++r) {
        float mm = acc[0][r];
#pragma unroll
        for (int kt = 1; kt < 16; ++kt) mm = fmaxf(mm, acc[kt][r]);
#pragma unroll
        for (int off = 1; off < 16; off <<= 1) mm = fmaxf(mm, __shfl_xor(mm, off));
        m[r] = mm;
    }
    if ((lane & 15) == 0) {
#pragma unroll
        for (int r = 0; r < 4; ++r) redm[w][(lane >> 4) * 4 + r] = m[r];
    }
    __syncthreads();

    float mx[4];
#pragma unroll
    for (int r = 0; r < 4; ++r) {
        const int q = (lane >> 4) * 4 + r;
        float mm = redm[0][q];
#pragma unroll
        for (int ww = 1; ww < 8; ++ww) mm = fmaxf(mm, redm[ww][q]);
        mx[r] = mm;
    }

    // exp in place + row sum
    float s[4] = {0.f, 0.f, 0.f, 0.f};
#pragma unroll
    for (int kt = 0; kt < 16; ++kt) {
#pragma unroll
        for (int r = 0; r < 4; ++r) {
            const float p = __expf(acc[kt][r] - mx[r]);
            acc[kt][r] = p;
            s[r] += p;
        }
    }
#pragma unroll
    for (int r = 0; r < 4; ++r) {
#pragma unroll
        for (int off = 1; off < 16; off <<= 1) s[r] += __shfl_xor(s[r], off);
    }
    if ((lane & 15) == 0) {
#pragma unroll
        for (int r = 0; r < 4; ++r) reds[w][(lane >> 4) * 4 + r] = s[r];
    }
    __syncthreads();

    float rinv[4];
#pragma unroll
    for (int r = 0; r < 4; ++r) {
        const int q = (lane >> 4) * 4 + r;
        float ss = reds[0][q];
#pragma unroll
        for (int ww = 1; ww < 8; ++ww) ss += reds[ww][q];
        rinv[r] = 1.f / ss;
    }

    // normalized fp32 attn write: per (kt,r) lanes 0-15 write 64B contiguous
    float* attn_base = attn_out + ((size_t)bh * SEQ + q0) * SEQ;
#pragma unroll
    for (int kt = 0; kt < 16; ++kt) {
#pragma unroll
        for (int r = 0; r < 4; ++r) {
            const int q = (lane >> 4) * 4 + r;
            attn_base[(size_t)q * SEQ + w * 256 + kt * 16 + (lane & 15)] = acc[kt][r] * rinv[r];
        }
    }
}

// ---------------- V panel transpose: Vh[B,S,H*64] -> Vt[32][64 d][2048 k] bf16 ----------------
__global__ __launch_bounds__(256) void transpose_v(const ushort* __restrict__ Vh,
                                                   ushort* __restrict__ Vt) {
    __shared__ ushort tile[64][80];   // 80 keeps 16B row alignment
    const int t  = threadIdx.x;
    const int bh = blockIdx.x;
    const int k0 = blockIdx.y * 64;
    const int b  = bh >> 4;
    const int h  = bh & 15;
    const size_t panel = (size_t)b * SEQ * DM + (size_t)h * DEPTH;

    {
        const int k = t >> 2, dc = (t & 3) * 16;
        const ushort* src = Vh + panel + (size_t)(k0 + k) * DM + dc;
        *(bf16x8*)&tile[k][dc]     = *(const bf16x8*)src;
        *(bf16x8*)&tile[k][dc + 8] = *(const bf16x8*)(src + 8);
    }
    __syncthreads();
    {
        const int d = t >> 2, kc = (t & 3) * 16;
        bf16x8 o0, o1;
#pragma unroll
        for (int j = 0; j < 8; ++j) o0[j] = tile[kc + j][d];
#pragma unroll
        for (int j = 0; j < 8; ++j) o1[j] = tile[kc + 8 + j][d];
        ushort* dst = Vt + ((size_t)bh * DEPTH + d) * SEQ + k0 + kc;
        *(bf16x8*)dst       = o0;
        *(bf16x8*)(dst + 8) = o1;
    }
}

// ---------------- PV: ctx[q][d] = attn_f32[q][k] @ Vt[d][k], per (b,h) ----------------
// 256 threads (4 waves), tile 128q x 64d, K-loop 32. Wave w owns q-rows [w*32, w*32+32).
__global__ __launch_bounds__(256) void pv_kernel(const float* __restrict__ attn,
                                                 const ushort* __restrict__ Vt,
                                                 ushort* __restrict__ Ctx) {
    __shared__ __align__(16) ushort As[128 * 32];  // P tile bf16, 8 KB
    __shared__ __align__(16) ushort Bs[64 * 32];   // V^T tile bf16, 4 KB

    const int t    = threadIdx.x;
    const int lane = t & 63;
    const int w    = t >> 6;
    const int bh   = blockIdx.x;      // 0..31
    const int q0   = blockIdx.y * 128;
    const int b    = bh >> 4;
    const int h    = bh & 15;

    f32x4 acc[2][4];
#pragma unroll
    for (int mi = 0; mi < 2; ++mi)
#pragma unroll
        for (int ni = 0; ni < 4; ++ni) acc[mi][ni] = (f32x4){0.f, 0.f, 0.f, 0.f};

    const float*  arow = attn + ((size_t)bh * SEQ + q0 + (t >> 1)) * SEQ + (t & 1) * 16;
    const ushort* vrow = Vt + ((size_t)bh * DEPTH + (t >> 2)) * SEQ + (t & 3) * 8;

    for (int k0 = 0; k0 < SEQ; k0 += 32) {
        // stage A: fp32 attn -> bf16 LDS, thread covers row t>>1, cols (t&1)*16..+15
        const float4 a0 = *(const float4*)(arow + k0);
        const float4 a1 = *(const float4*)(arow + k0 + 4);
        const float4 a2 = *(const float4*)(arow + k0 + 8);
        const float4 a3 = *(const float4*)(arow + k0 + 12);
        bf16x8 p0, p1;
        p0[0] = f2b(a0.x); p0[1] = f2b(a0.y); p0[2] = f2b(a0.z); p0[3] = f2b(a0.w);
        p0[4] = f2b(a1.x); p0[5] = f2b(a1.y); p0[6] = f2b(a1.z); p0[7] = f2b(a1.w);
        p1[0] = f2b(a2.x); p1[1] = f2b(a2.y); p1[2] = f2b(a2.z); p1[3] = f2b(a2.w);
        p1[4] = f2b(a3.x); p1[5] = f2b(a3.y); p1[6] = f2b(a3.z); p1[7] = f2b(a3.w);
        *(bf16x8*)&As[(t >> 1) * 32 + (t & 1) * 16]     = p0;
        *(bf16x8*)&As[(t >> 1) * 32 + (t & 1) * 16 + 8] = p1;
        // stage B: Vt tile [64][32] via global_load_lds (linear: lds byte = t*16)
        gload_lds16(vrow + k0, &Bs[w * 512]);
        __syncthreads();

        bf16x8 af[2], bfr[4];
#pragma unroll
        for (int mi = 0; mi < 2; ++mi)
            af[mi] = *(const bf16x8*)&As[(w * 32 + mi * 16 + (lane & 15)) * 32 + (lane >> 4) * 8];
#pragma unroll
        for (int ni = 0; ni < 4; ++ni)
            bfr[ni] = *(const bf16x8*)&Bs[(ni * 16 + (lane & 15)) * 32 + (lane >> 4) * 8];
#pragma unroll
        for (int mi = 0; mi < 2; ++mi)
#pragma unroll
            for (int ni = 0; ni < 4; ++ni)
                acc[mi][ni] = __builtin_amdgcn_mfma_f32_16x16x32_bf16(af[mi], bfr[ni], acc[mi][ni], 0, 0, 0);
        __syncthreads();
    }

    // write ctx bf16 into [B,S,H*64] panel layout
#pragma unroll
    for (int mi = 0; mi < 2; ++mi) {
        const int row = q0 + w * 32 + mi * 16 + (lane >> 4) * 4;
#pragma unroll
        for (int ni = 0; ni < 4; ++ni) {
            const int col = ni * 16 + (lane & 15);
#pragma unroll
            for (int r = 0; r < 4; ++r) {
                Ctx[(size_t)(b * SEQ + row + r) * DM + h * DEPTH + col] = f2b(acc[mi][ni][r]);
            }
        }
    }
}

extern "C" void kernel_launch(void* const* d_in, const int* in_sizes, int n_in,
                              void* d_out, int out_size, void* d_ws, size_t ws_size,
                              hipStream_t stream) {
    const float* x  = (const float*)d_in[0];
    const float* wq = (const float*)d_in[1];
    const float* bq = (const float*)d_in[2];
    const float* wk = (const float*)d_in[3];
    const float* bk = (const float*)d_in[4];
    const float* wv = (const float*)d_in[5];
    const float* bv = (const float*)d_in[6];
    const float* wo = (const float*)d_in[7];
    const float* bo = (const float*)d_in[8];

    float* out  = (float*)d_out;                          // [2,2048,1024]
    float* attn = out + (size_t)MROWS * DM;               // [2,16,2048,2048] fp32

    ushort* ws  = (ushort*)d_ws;
    ushort* xb  = ws;                       // 4096x1024 bf16
    ushort* wqt = xb + (size_t)MROWS * DM;
    ushort* wkt = wqt + (size_t)DM * DM;
    ushort* wvt = wkt + (size_t)DM * DM;
    ushort* wot = wvt + (size_t)DM * DM;
    ushort* Qh  = wot + (size_t)DM * DM;    // 4096x1024 bf16 ([B,S,H*64])
    ushort* Kh  = Qh + (size_t)MROWS * DM;
    ushort* Vh  = Kh + (size_t)MROWS * DM;
    ushort* cxb = Vh + (size_t)MROWS * DM;
    ushort* Vt  = cxb + (size_t)MROWS * DM; // [32][64][2048] bf16

    const dim3 tgrid(DM / 32, DM / 32);
    convert_f32_bf16<<<dim3(MROWS * DM / 4 / 256), 256, 0, stream>>>(x, xb, MROWS * DM / 4);
    transpose_convert<<<tgrid, 256, 0, stream>>>(wq, wqt);
    transpose_convert<<<tgrid, 256, 0, stream>>>(wk, wkt);
    transpose_convert<<<tgrid, 256, 0, stream>>>(wv, wvt);
    transpose_convert<<<tgrid, 256, 0, stream>>>(wo, wot);

    const dim3 ggrid(DM / 128, MROWS / 128);  // (8,32)
    gemm_mfma<true><<<ggrid, 256, 0, stream>>>(xb, wqt, bq, Qh);
    gemm_mfma<true><<<ggrid, 256, 0, stream>>>(xb, wkt, bk, Kh);
    gemm_mfma<true><<<ggrid, 256, 0, stream>>>(xb, wvt, bv, Vh);

    transpose_v<<<dim3(BATCH * NH, SEQ / 64), 256, 0, stream>>>(Vh, Vt);

    qk_softmax_kernel<<<dim3(BATCH * NH, SEQ / 16), 512, 0, stream>>>(Qh, Kh, attn);

    pv_kernel<<<dim3(BATCH * NH, SEQ / 128), 256, 0, stream>>>(attn, Vt, cxb);

    gemm_mfma<false><<<ggrid, 256, 0, stream>>>(cxb, wot, bo, out);
}

// Round 5
// 409.706 us; speedup vs baseline: 8.9437x; 1.2701x over previous
//
#include <hip/hip_runtime.h>
#include <hip/hip_bf16.h>

#define SEQ 2048
#define BATCH 2
#define NH 16
#define DM 1024
#define DEPTH 64
#define MROWS (BATCH * SEQ)   // 4096

typedef __attribute__((ext_vector_type(8))) short bf16x8;
typedef __attribute__((ext_vector_type(4))) float f32x4;

__device__ __forceinline__ float b2f(ushort u) {
    union { uint i; float f; } v; v.i = ((uint)u) << 16; return v.f;
}
__device__ __forceinline__ ushort f2b(float f) {
    __hip_bfloat16 h = __float2bfloat16(f);
    return *reinterpret_cast<ushort*>(&h);
}

__device__ __forceinline__ void gload_lds16(const void* g, void* l) {
    __builtin_amdgcn_global_load_lds((const __attribute__((address_space(1))) void*)g,
                                     (__attribute__((address_space(3))) void*)l, 16, 0, 0);
}

// ---------------- fp32 -> bf16 elementwise ----------------
__global__ __launch_bounds__(256) void convert_f32_bf16(const float* __restrict__ in,
                                                        ushort* __restrict__ outp, int n4) {
    int i = blockIdx.x * 256 + threadIdx.x;
    if (i < n4) {
        const float4 v = ((const float4*)in)[i];
        ushort4 o;
        o.x = f2b(v.x); o.y = f2b(v.y); o.z = f2b(v.z); o.w = f2b(v.w);
        ((ushort4*)outp)[i] = o;
    }
}

// ---------------- fp32 W[K][N] -> bf16 Wt[N][K] ----------------
__global__ __launch_bounds__(256) void transpose_convert(const float* __restrict__ W,
                                                         ushort* __restrict__ Wt) {
    __shared__ float tile[32][33];
    const int bx = blockIdx.x * 32;  // n base
    const int by = blockIdx.y * 32;  // k base
    const int tx = threadIdx.x & 31, ty = threadIdx.x >> 5;
#pragma unroll
    for (int i = 0; i < 32; i += 8)
        tile[ty + i][tx] = W[(size_t)(by + ty + i) * DM + bx + tx];
    __syncthreads();
#pragma unroll
    for (int i = 0; i < 32; i += 8)
        Wt[(size_t)(bx + ty + i) * DM + by + tx] = f2b(tile[tx][ty + i]);
}

// ---------------- bf16 MFMA GEMM (verified R3): C = A @ Wt^T + bias ----------------
template <bool BF16OUT>
__global__ __launch_bounds__(256) void gemm_mfma(const ushort* __restrict__ A,
                                                 const ushort* __restrict__ Wt,
                                                 const float* __restrict__ bias,
                                                 void* __restrict__ Cout) {
    __shared__ __align__(16) ushort As[128 * 32];
    __shared__ __align__(16) ushort Bs[128 * 32];

    const int t    = threadIdx.x;
    const int lane = t & 63;
    const int w    = t >> 6;
    const int wr   = w >> 1, wc = w & 1;
    const int row0 = blockIdx.y * 128;
    const int col0 = blockIdx.x * 128;

    f32x4 acc[4][4];
#pragma unroll
    for (int mi = 0; mi < 4; ++mi)
#pragma unroll
        for (int ni = 0; ni < 4; ++ni) acc[mi][ni] = (f32x4){0.f, 0.f, 0.f, 0.f};

    const int sr = t >> 2;
    const int sc = (t & 3) * 8;

    for (int k0 = 0; k0 < DM; k0 += 32) {
        gload_lds16(&A[(size_t)(row0 + sr) * DM + k0 + sc],       &As[w * 512]);
        gload_lds16(&A[(size_t)(row0 + 64 + sr) * DM + k0 + sc],  &As[2048 + w * 512]);
        gload_lds16(&Wt[(size_t)(col0 + sr) * DM + k0 + sc],      &Bs[w * 512]);
        gload_lds16(&Wt[(size_t)(col0 + 64 + sr) * DM + k0 + sc], &Bs[2048 + w * 512]);
        __syncthreads();

        bf16x8 af[4], bfr[4];
#pragma unroll
        for (int mi = 0; mi < 4; ++mi)
            af[mi] = *(const bf16x8*)&As[(wr * 64 + mi * 16 + (lane & 15)) * 32 + (lane >> 4) * 8];
#pragma unroll
        for (int ni = 0; ni < 4; ++ni)
            bfr[ni] = *(const bf16x8*)&Bs[(wc * 64 + ni * 16 + (lane & 15)) * 32 + (lane >> 4) * 8];
#pragma unroll
        for (int mi = 0; mi < 4; ++mi)
#pragma unroll
            for (int ni = 0; ni < 4; ++ni)
                acc[mi][ni] = __builtin_amdgcn_mfma_f32_16x16x32_bf16(af[mi], bfr[ni], acc[mi][ni], 0, 0, 0);
        __syncthreads();
    }

    float bb[4];
#pragma unroll
    for (int ni = 0; ni < 4; ++ni) bb[ni] = bias[col0 + wc * 64 + ni * 16 + (lane & 15)];

#pragma unroll
    for (int mi = 0; mi < 4; ++mi) {
        const int row = row0 + wr * 64 + mi * 16 + (lane >> 4) * 4;
#pragma unroll
        for (int ni = 0; ni < 4; ++ni) {
            const int col = col0 + wc * 64 + ni * 16 + (lane & 15);
#pragma unroll
            for (int r = 0; r < 4; ++r) {
                const float v = acc[mi][ni][r] + bb[ni];
                if (BF16OUT)
                    ((ushort*)Cout)[(size_t)(row + r) * DM + col] = f2b(v);
                else
                    ((float*)Cout)[(size_t)(row + r) * DM + col] = v;
            }
        }
    }
}

// ---------------- V panel transpose: Vh[B,S,H*64] -> Vt[32][64 d][2048 k] bf16 ----------------
__global__ __launch_bounds__(256) void transpose_v(const ushort* __restrict__ Vh,
                                                   ushort* __restrict__ Vt) {
    __shared__ ushort tile[64][80];
    const int t  = threadIdx.x;
    const int bh = blockIdx.x;
    const int k0 = blockIdx.y * 64;
    const int b  = bh >> 4;
    const int h  = bh & 15;
    const size_t panel = (size_t)b * SEQ * DM + (size_t)h * DEPTH;

    {
        const int k = t >> 2, dc = (t & 3) * 16;
        const ushort* src = Vh + panel + (size_t)(k0 + k) * DM + dc;
        *(bf16x8*)&tile[k][dc]     = *(const bf16x8*)src;
        *(bf16x8*)&tile[k][dc + 8] = *(const bf16x8*)(src + 8);
    }
    __syncthreads();
    {
        const int d = t >> 2, kc = (t & 3) * 16;
        bf16x8 o0, o1;
#pragma unroll
        for (int j = 0; j < 8; ++j) o0[j] = tile[kc + j][d];
#pragma unroll
        for (int j = 0; j < 8; ++j) o1[j] = tile[kc + 8 + j][d];
        ushort* dst = Vt + ((size_t)bh * DEPTH + d) * SEQ + k0 + kc;
        *(bf16x8*)dst       = o0;
        *(bf16x8*)(dst + 8) = o1;
    }
}

// ---------------- fused attention: QK^T (MFMA) + softmax + attn write + PV (MFMA) ----------------
// Block: 512 threads (8 waves), one (b,h) x 16 q-rows. Wave w owns keys [w*256, w*256+256).
// After softmax, P round-trips through a swizzled 64KB LDS tile to become MFMA A-fragments.
// LDS swizzle: byte_in_row ^= (row&7)<<4 — keeps 16B alignment, spreads A-frag ds_read_b128
// across all 32 banks (unswizzled would be 16-way conflict).
__global__ __launch_bounds__(512, 4) void attn_fused_kernel(const ushort* __restrict__ Qh,
                                                            const ushort* __restrict__ Kh,
                                                            const ushort* __restrict__ Vt,
                                                            float* __restrict__ attn_out,
                                                            ushort* __restrict__ Ctx) {
    __shared__ __align__(16) ushort P_lds[16 * 2048];   // exactly 64 KB
    float* red = (float*)P_lds;   // phase-2 overlay: redm = red[0..127], reds = red[128..255]

    const int t    = threadIdx.x;
    const int lane = t & 63;
    const int w    = t >> 6;          // 0..7
    const int bh   = blockIdx.x;      // 0..31
    const int qt   = blockIdx.y;      // 0..127
    const int b    = bh >> 4;
    const int h    = bh & 15;
    const int q0   = qt * 16;

    const size_t panel = (size_t)b * SEQ * DM + (size_t)h * DEPTH;

    // ---- phase 1: QK^T, this wave's 256 keys; lane holds S[q=(lane>>4)*4+r][k=w*256+kt*16+(lane&15)]
    const ushort* Qrow = Qh + panel + (size_t)(q0 + (lane & 15)) * DM + (lane >> 4) * 8;
    const bf16x8 qf0 = *(const bf16x8*)Qrow;
    const bf16x8 qf1 = *(const bf16x8*)(Qrow + 32);

    f32x4 acc[16];
#pragma unroll
    for (int kt = 0; kt < 16; ++kt) acc[kt] = (f32x4){0.f, 0.f, 0.f, 0.f};

    const ushort* Kbase = Kh + panel + (size_t)(w * 256) * DM + (lane >> 4) * 8;
#pragma unroll
    for (int kt = 0; kt < 16; ++kt) {
        const ushort* Kr = Kbase + (size_t)(kt * 16 + (lane & 15)) * DM;
        const bf16x8 kf0 = *(const bf16x8*)Kr;
        const bf16x8 kf1 = *(const bf16x8*)(Kr + 32);
        acc[kt] = __builtin_amdgcn_mfma_f32_16x16x32_bf16(qf0, kf0, acc[kt], 0, 0, 0);
        acc[kt] = __builtin_amdgcn_mfma_f32_16x16x32_bf16(qf1, kf1, acc[kt], 0, 0, 0);
    }

#pragma unroll
    for (int kt = 0; kt < 16; ++kt) {
        acc[kt][0] *= 0.125f; acc[kt][1] *= 0.125f;
        acc[kt][2] *= 0.125f; acc[kt][3] *= 0.125f;
    }

    // ---- phase 2: softmax stats (wave-local shuffle + tiny LDS cross-wave combine)
    float m[4];
#pragma unroll
    for (int r = 0; r < 4; ++r) {
        float mm = acc[0][r];
#pragma unroll
        for (int kt = 1; kt < 16; ++kt) mm = fmaxf(mm, acc[kt][r]);
#pragma unroll
        for (int off = 1; off < 16; off <<= 1) mm = fmaxf(mm, __shfl_xor(mm, off));
        m[r] = mm;
    }
    if ((lane & 15) == 0) {
#pragma unroll
        for (int r = 0; r < 4; ++r) red[w * 16 + (lane >> 4) * 4 + r] = m[r];
    }
    __syncthreads();

    float mx[4];
#pragma unroll
    for (int r = 0; r < 4; ++r) {
        const int q = (lane >> 4) * 4 + r;
        float mm = red[q];
#pragma unroll
        for (int ww = 1; ww < 8; ++ww) mm = fmaxf(mm, red[ww * 16 + q]);
        mx[r] = mm;
    }

    float s[4] = {0.f, 0.f, 0.f, 0.f};
#pragma unroll
    for (int kt = 0; kt < 16; ++kt) {
#pragma unroll
        for (int r = 0; r < 4; ++r) {
            const float p = __expf(acc[kt][r] - mx[r]);
            acc[kt][r] = p;
            s[r] += p;
        }
    }
#pragma unroll
    for (int r = 0; r < 4; ++r) {
#pragma unroll
        for (int off = 1; off < 16; off <<= 1) s[r] += __shfl_xor(s[r], off);
    }
    if ((lane & 15) == 0) {
#pragma unroll
        for (int r = 0; r < 4; ++r) red[128 + w * 16 + (lane >> 4) * 4 + r] = s[r];
    }
    __syncthreads();

    float rinv[4];
#pragma unroll
    for (int r = 0; r < 4; ++r) {
        const int q = (lane >> 4) * 4 + r;
        float ss = red[128 + q];
#pragma unroll
        for (int ww = 1; ww < 8; ++ww) ss += red[128 + ww * 16 + q];
        rinv[r] = 1.f / ss;
    }
    __syncthreads();   // everyone has rinv; red overlay now dead -> P_lds writable

    // ---- phase 3: normalized P -> LDS (bf16, swizzled) + attn global (fp32, nontemporal)
    float* attn_base = attn_out + ((size_t)bh * SEQ + q0) * SEQ;
    char* Pb = (char*)P_lds;
#pragma unroll
    for (int kt = 0; kt < 16; ++kt) {
#pragma unroll
        for (int r = 0; r < 4; ++r) {
            const int q = (lane >> 4) * 4 + r;
            const int k = w * 256 + kt * 16 + (lane & 15);
            const float p = acc[kt][r] * rinv[r];
            const int byte_in_row = (k * 2) ^ ((q & 7) << 4);
            *(ushort*)(Pb + q * 4096 + byte_in_row) = f2b(p);
            __builtin_nontemporal_store(p, &attn_base[(size_t)q * SEQ + k]);
        }
    }
    __syncthreads();

    // ---- phase 4: PV. Wave w: ctx_partial[16 q][64 d] over its 256 keys.
    // A-frag: P[q=lane&15][kofs..] from swizzled LDS; B-frag: Vt[d][kofs..] from global (L2-hot).
    f32x4 ctx[4];
#pragma unroll
    for (int ni = 0; ni < 4; ++ni) ctx[ni] = (f32x4){0.f, 0.f, 0.f, 0.f};

    const ushort* Vtp = Vt + (size_t)bh * DEPTH * SEQ;
#pragma unroll
    for (int s8 = 0; s8 < 8; ++s8) {
        const int kofs = w * 256 + s8 * 32 + (lane >> 4) * 8;
        const int row  = lane & 15;
        const bf16x8 af = *(const bf16x8*)(Pb + row * 4096 + ((kofs * 2) ^ ((row & 7) << 4)));
#pragma unroll
        for (int ni = 0; ni < 4; ++ni) {
            const bf16x8 bfr = *(const bf16x8*)&Vtp[(size_t)(ni * 16 + (lane & 15)) * SEQ + kofs];
            ctx[ni] = __builtin_amdgcn_mfma_f32_16x16x32_bf16(af, bfr, ctx[ni], 0, 0, 0);
        }
    }
    __syncthreads();   // all P_lds reads done; reuse as f32 partials [8][16][64]

    // ---- phase 5: cross-wave reduce + ctx write
    float* part = (float*)P_lds;
#pragma unroll
    for (int ni = 0; ni < 4; ++ni) {
#pragma unroll
        for (int r = 0; r < 4; ++r) {
            part[(w * 16 + (lane >> 4) * 4 + r) * 64 + ni * 16 + (lane & 15)] = ctx[ni][r];
        }
    }
    __syncthreads();

#pragma unroll
    for (int idx = t; idx < 1024; idx += 512) {
        const int q = idx >> 6, d = idx & 63;
        float ssum = 0.f;
#pragma unroll
        for (int ww = 0; ww < 8; ++ww) ssum += part[ww * 1024 + idx];
        Ctx[(size_t)(b * SEQ + q0 + q) * DM + h * DEPTH + d] = f2b(ssum);
    }
}

extern "C" void kernel_launch(void* const* d_in, const int* in_sizes, int n_in,
                              void* d_out, int out_size, void* d_ws, size_t ws_size,
                              hipStream_t stream) {
    const float* x  = (const float*)d_in[0];
    const float* wq = (const float*)d_in[1];
    const float* bq = (const float*)d_in[2];
    const float* wk = (const float*)d_in[3];
    const float* bk = (const float*)d_in[4];
    const float* wv = (const float*)d_in[5];
    const float* bv = (const float*)d_in[6];
    const float* wo = (const float*)d_in[7];
    const float* bo = (const float*)d_in[8];

    float* out  = (float*)d_out;                          // [2,2048,1024]
    float* attn = out + (size_t)MROWS * DM;               // [2,16,2048,2048] fp32

    ushort* ws  = (ushort*)d_ws;
    ushort* xb  = ws;                       // 4096x1024 bf16
    ushort* wqt = xb + (size_t)MROWS * DM;
    ushort* wkt = wqt + (size_t)DM * DM;
    ushort* wvt = wkt + (size_t)DM * DM;
    ushort* wot = wvt + (size_t)DM * DM;
    ushort* Qh  = wot + (size_t)DM * DM;    // 4096x1024 bf16 ([B,S,H*64])
    ushort* Kh  = Qh + (size_t)MROWS * DM;
    ushort* Vh  = Kh + (size_t)MROWS * DM;
    ushort* cxb = Vh + (size_t)MROWS * DM;
    ushort* Vt  = cxb + (size_t)MROWS * DM; // [32][64][2048] bf16

    const dim3 tgrid(DM / 32, DM / 32);
    convert_f32_bf16<<<dim3(MROWS * DM / 4 / 256), 256, 0, stream>>>(x, xb, MROWS * DM / 4);
    transpose_convert<<<tgrid, 256, 0, stream>>>(wq, wqt);
    transpose_convert<<<tgrid, 256, 0, stream>>>(wk, wkt);
    transpose_convert<<<tgrid, 256, 0, stream>>>(wv, wvt);
    transpose_convert<<<tgrid, 256, 0, stream>>>(wo, wot);

    const dim3 ggrid(DM / 128, MROWS / 128);  // (8,32)
    gemm_mfma<true><<<ggrid, 256, 0, stream>>>(xb, wqt, bq, Qh);
    gemm_mfma<true><<<ggrid, 256, 0, stream>>>(xb, wkt, bk, Kh);
    gemm_mfma<true><<<ggrid, 256, 0, stream>>>(xb, wvt, bv, Vh);

    transpose_v<<<dim3(BATCH * NH, SEQ / 64), 256, 0, stream>>>(Vh, Vt);

    attn_fused_kernel<<<dim3(BATCH * NH, SEQ / 16), 512, 0, stream>>>(Qh, Kh, Vt, attn, cxb);

    gemm_mfma<false><<<ggrid, 256, 0, stream>>>(cxb, wot, bo, out);
}

// Round 6
// 363.377 us; speedup vs baseline: 10.0840x; 1.1275x over previous
//
#include <hip/hip_runtime.h>
#include <hip/hip_bf16.h>

#define SEQ 2048
#define BATCH 2
#define NH 16
#define DM 1024
#define DEPTH 64
#define MROWS (BATCH * SEQ)   // 4096

typedef __attribute__((ext_vector_type(8))) short bf16x8;
typedef __attribute__((ext_vector_type(4))) float f32x4;

__device__ __forceinline__ float b2f(ushort u) {
    union { uint i; float f; } v; v.i = ((uint)u) << 16; return v.f;
}
__device__ __forceinline__ ushort f2b(float f) {
    __hip_bfloat16 h = __float2bfloat16(f);
    return *reinterpret_cast<ushort*>(&h);
}

__device__ __forceinline__ void gload_lds16(const void* g, void* l) {
    __builtin_amdgcn_global_load_lds((const __attribute__((address_space(1))) void*)g,
                                     (__attribute__((address_space(3))) void*)l, 16, 0, 0);
}

// ---------------- fp32 -> bf16 elementwise ----------------
__global__ __launch_bounds__(256) void convert_f32_bf16(const float* __restrict__ in,
                                                        ushort* __restrict__ outp, int n4) {
    int i = blockIdx.x * 256 + threadIdx.x;
    if (i < n4) {
        const float4 v = ((const float4*)in)[i];
        ushort4 o;
        o.x = f2b(v.x); o.y = f2b(v.y); o.z = f2b(v.z); o.w = f2b(v.w);
        ((ushort4*)outp)[i] = o;
    }
}

// ---------------- 4x fused: fp32 W[K][N] -> bf16 Wt[N][K], z selects weight ----------------
__global__ __launch_bounds__(256) void transpose_convert4(const float* __restrict__ w0,
                                                          const float* __restrict__ w1,
                                                          const float* __restrict__ w2,
                                                          const float* __restrict__ w3,
                                                          ushort* __restrict__ WtBase) {
    __shared__ float tile[32][33];
    const int z = blockIdx.z;
    const float* W = (z == 0) ? w0 : (z == 1) ? w1 : (z == 2) ? w2 : w3;
    ushort* Wt = WtBase + (size_t)z * DM * DM;
    const int bx = blockIdx.x * 32;  // n base
    const int by = blockIdx.y * 32;  // k base
    const int tx = threadIdx.x & 31, ty = threadIdx.x >> 5;
#pragma unroll
    for (int i = 0; i < 32; i += 8)
        tile[ty + i][tx] = W[(size_t)(by + ty + i) * DM + bx + tx];
    __syncthreads();
#pragma unroll
    for (int i = 0; i < 32; i += 8)
        Wt[(size_t)(bx + ty + i) * DM + by + tx] = f2b(tile[tx][ty + i]);
}

// ---------------- fused QKV GEMM: [4096,1024] @ [1024,3072] + bias -> bf16 ----------------
__global__ __launch_bounds__(256) void gemm_qkv_mfma(const ushort* __restrict__ A,
                                                     const ushort* __restrict__ WtAll,
                                                     const float* __restrict__ bq,
                                                     const float* __restrict__ bk,
                                                     const float* __restrict__ bv,
                                                     ushort* __restrict__ OutBase) {
    __shared__ __align__(16) ushort As[128 * 32];
    __shared__ __align__(16) ushort Bs[128 * 32];

    const int t    = threadIdx.x;
    const int lane = t & 63;
    const int w    = t >> 6;
    const int wr   = w >> 1, wc = w & 1;
    const int row0 = blockIdx.y * 128;
    const int col0 = blockIdx.x * 128;           // 0..2944
    const int bank = col0 >> 10;                 // 0,1,2
    const float* bias = (bank == 0) ? bq : (bank == 1) ? bk : bv;
    const int ccol0 = col0 & 1023;
    ushort* Cout = OutBase + (size_t)bank * MROWS * DM;

    f32x4 acc[4][4];
#pragma unroll
    for (int mi = 0; mi < 4; ++mi)
#pragma unroll
        for (int ni = 0; ni < 4; ++ni) acc[mi][ni] = (f32x4){0.f, 0.f, 0.f, 0.f};

    const int sr = t >> 2;
    const int sc = (t & 3) * 8;

    for (int k0 = 0; k0 < DM; k0 += 32) {
        gload_lds16(&A[(size_t)(row0 + sr) * DM + k0 + sc],          &As[w * 512]);
        gload_lds16(&A[(size_t)(row0 + 64 + sr) * DM + k0 + sc],     &As[2048 + w * 512]);
        gload_lds16(&WtAll[(size_t)(col0 + sr) * DM + k0 + sc],      &Bs[w * 512]);
        gload_lds16(&WtAll[(size_t)(col0 + 64 + sr) * DM + k0 + sc], &Bs[2048 + w * 512]);
        __syncthreads();

        bf16x8 af[4], bfr[4];
#pragma unroll
        for (int mi = 0; mi < 4; ++mi)
            af[mi] = *(const bf16x8*)&As[(wr * 64 + mi * 16 + (lane & 15)) * 32 + (lane >> 4) * 8];
#pragma unroll
        for (int ni = 0; ni < 4; ++ni)
            bfr[ni] = *(const bf16x8*)&Bs[(wc * 64 + ni * 16 + (lane & 15)) * 32 + (lane >> 4) * 8];
#pragma unroll
        for (int mi = 0; mi < 4; ++mi)
#pragma unroll
            for (int ni = 0; ni < 4; ++ni)
                acc[mi][ni] = __builtin_amdgcn_mfma_f32_16x16x32_bf16(af[mi], bfr[ni], acc[mi][ni], 0, 0, 0);
        __syncthreads();
    }

    float bb[4];
#pragma unroll
    for (int ni = 0; ni < 4; ++ni) bb[ni] = bias[ccol0 + wc * 64 + ni * 16 + (lane & 15)];

#pragma unroll
    for (int mi = 0; mi < 4; ++mi) {
        const int row = row0 + wr * 64 + mi * 16 + (lane >> 4) * 4;
#pragma unroll
        for (int ni = 0; ni < 4; ++ni) {
            const int col = ccol0 + wc * 64 + ni * 16 + (lane & 15);
#pragma unroll
            for (int r = 0; r < 4; ++r)
                Cout[(size_t)(row + r) * DM + col] = f2b(acc[mi][ni][r] + bb[ni]);
        }
    }
}

// ---------------- bf16 MFMA GEMM: C = A @ Wt^T + bias, fp32 out ----------------
__global__ __launch_bounds__(256) void gemm_mfma_f32(const ushort* __restrict__ A,
                                                     const ushort* __restrict__ Wt,
                                                     const float* __restrict__ bias,
                                                     float* __restrict__ Cout) {
    __shared__ __align__(16) ushort As[128 * 32];
    __shared__ __align__(16) ushort Bs[128 * 32];

    const int t    = threadIdx.x;
    const int lane = t & 63;
    const int w    = t >> 6;
    const int wr   = w >> 1, wc = w & 1;
    const int row0 = blockIdx.y * 128;
    const int col0 = blockIdx.x * 128;

    f32x4 acc[4][4];
#pragma unroll
    for (int mi = 0; mi < 4; ++mi)
#pragma unroll
        for (int ni = 0; ni < 4; ++ni) acc[mi][ni] = (f32x4){0.f, 0.f, 0.f, 0.f};

    const int sr = t >> 2;
    const int sc = (t & 3) * 8;

    for (int k0 = 0; k0 < DM; k0 += 32) {
        gload_lds16(&A[(size_t)(row0 + sr) * DM + k0 + sc],       &As[w * 512]);
        gload_lds16(&A[(size_t)(row0 + 64 + sr) * DM + k0 + sc],  &As[2048 + w * 512]);
        gload_lds16(&Wt[(size_t)(col0 + sr) * DM + k0 + sc],      &Bs[w * 512]);
        gload_lds16(&Wt[(size_t)(col0 + 64 + sr) * DM + k0 + sc], &Bs[2048 + w * 512]);
        __syncthreads();

        bf16x8 af[4], bfr[4];
#pragma unroll
        for (int mi = 0; mi < 4; ++mi)
            af[mi] = *(const bf16x8*)&As[(wr * 64 + mi * 16 + (lane & 15)) * 32 + (lane >> 4) * 8];
#pragma unroll
        for (int ni = 0; ni < 4; ++ni)
            bfr[ni] = *(const bf16x8*)&Bs[(wc * 64 + ni * 16 + (lane & 15)) * 32 + (lane >> 4) * 8];
#pragma unroll
        for (int mi = 0; mi < 4; ++mi)
#pragma unroll
            for (int ni = 0; ni < 4; ++ni)
                acc[mi][ni] = __builtin_amdgcn_mfma_f32_16x16x32_bf16(af[mi], bfr[ni], acc[mi][ni], 0, 0, 0);
        __syncthreads();
    }

    float bb[4];
#pragma unroll
    for (int ni = 0; ni < 4; ++ni) bb[ni] = bias[col0 + wc * 64 + ni * 16 + (lane & 15)];

#pragma unroll
    for (int mi = 0; mi < 4; ++mi) {
        const int row = row0 + wr * 64 + mi * 16 + (lane >> 4) * 4;
#pragma unroll
        for (int ni = 0; ni < 4; ++ni) {
            const int col = col0 + wc * 64 + ni * 16 + (lane & 15);
#pragma unroll
            for (int r = 0; r < 4; ++r)
                Cout[(size_t)(row + r) * DM + col] = acc[mi][ni][r] + bb[ni];
        }
    }
}

// ---------------- V panel transpose: Vh[B,S,H*64] -> Vt[32][64 d][2048 k] bf16 ----------------
__global__ __launch_bounds__(256) void transpose_v(const ushort* __restrict__ Vh,
                                                   ushort* __restrict__ Vt) {
    __shared__ ushort tile[64][80];
    const int t  = threadIdx.x;
    const int bh = blockIdx.x;
    const int k0 = blockIdx.y * 64;
    const int b  = bh >> 4;
    const int h  = bh & 15;
    const size_t panel = (size_t)b * SEQ * DM + (size_t)h * DEPTH;

    {
        const int k = t >> 2, dc = (t & 3) * 16;
        const ushort* src = Vh + panel + (size_t)(k0 + k) * DM + dc;
        *(bf16x8*)&tile[k][dc]     = *(const bf16x8*)src;
        *(bf16x8*)&tile[k][dc + 8] = *(const bf16x8*)(src + 8);
    }
    __syncthreads();
    {
        const int d = t >> 2, kc = (t & 3) * 16;
        bf16x8 o0, o1;
#pragma unroll
        for (int j = 0; j < 8; ++j) o0[j] = tile[kc + j][d];
#pragma unroll
        for (int j = 0; j < 8; ++j) o1[j] = tile[kc + 8 + j][d];
        ushort* dst = Vt + ((size_t)bh * DEPTH + d) * SEQ + k0 + kc;
        *(bf16x8*)dst       = o0;
        *(bf16x8*)(dst + 8) = o1;
    }
}

// ---------------- fused attention (panel-major grid: qt fast, bh slow) ----------------
__global__ __launch_bounds__(512, 4) void attn_fused_kernel(const ushort* __restrict__ Qh,
                                                            const ushort* __restrict__ Kh,
                                                            const ushort* __restrict__ Vt,
                                                            float* __restrict__ attn_out,
                                                            ushort* __restrict__ Ctx) {
    __shared__ __align__(16) ushort P_lds[16 * 2048];   // 64 KB
    float* red = (float*)P_lds;

    const int t    = threadIdx.x;
    const int lane = t & 63;
    const int w    = t >> 6;          // 0..7
    const int qt   = blockIdx.x;      // 0..127 fast axis
    const int bh   = blockIdx.y;      // 0..31  slow axis -> panel-major dispatch
    const int b    = bh >> 4;
    const int h    = bh & 15;
    const int q0   = qt * 16;

    const size_t panel = (size_t)b * SEQ * DM + (size_t)h * DEPTH;

    const ushort* Qrow = Qh + panel + (size_t)(q0 + (lane & 15)) * DM + (lane >> 4) * 8;
    const bf16x8 qf0 = *(const bf16x8*)Qrow;
    const bf16x8 qf1 = *(const bf16x8*)(Qrow + 32);

    f32x4 acc[16];
#pragma unroll
    for (int kt = 0; kt < 16; ++kt) acc[kt] = (f32x4){0.f, 0.f, 0.f, 0.f};

    const ushort* Kbase = Kh + panel + (size_t)(w * 256) * DM + (lane >> 4) * 8;
#pragma unroll
    for (int kt = 0; kt < 16; ++kt) {
        const ushort* Kr = Kbase + (size_t)(kt * 16 + (lane & 15)) * DM;
        const bf16x8 kf0 = *(const bf16x8*)Kr;
        const bf16x8 kf1 = *(const bf16x8*)(Kr + 32);
        acc[kt] = __builtin_amdgcn_mfma_f32_16x16x32_bf16(qf0, kf0, acc[kt], 0, 0, 0);
        acc[kt] = __builtin_amdgcn_mfma_f32_16x16x32_bf16(qf1, kf1, acc[kt], 0, 0, 0);
    }

#pragma unroll
    for (int kt = 0; kt < 16; ++kt) {
        acc[kt][0] *= 0.125f; acc[kt][1] *= 0.125f;
        acc[kt][2] *= 0.125f; acc[kt][3] *= 0.125f;
    }

    float m[4];
#pragma unroll
    for (int r = 0; r < 4; ++r) {
        float mm = acc[0][r];
#pragma unroll
        for (int kt = 1; kt < 16; ++kt) mm = fmaxf(mm, acc[kt][r]);
#pragma unroll
        for (int off = 1; off < 16; off <<= 1) mm = fmaxf(mm, __shfl_xor(mm, off));
        m[r] = mm;
    }
    if ((lane & 15) == 0) {
#pragma unroll
        for (int r = 0; r < 4; ++r) red[w * 16 + (lane >> 4) * 4 + r] = m[r];
    }
    __syncthreads();

    float mx[4];
#pragma unroll
    for (int r = 0; r < 4; ++r) {
        const int q = (lane >> 4) * 4 + r;
        float mm = red[q];
#pragma unroll
        for (int ww = 1; ww < 8; ++ww) mm = fmaxf(mm, red[ww * 16 + q]);
        mx[r] = mm;
    }

    float s[4] = {0.f, 0.f, 0.f, 0.f};
#pragma unroll
    for (int kt = 0; kt < 16; ++kt) {
#pragma unroll
        for (int r = 0; r < 4; ++r) {
            const float p = __expf(acc[kt][r] - mx[r]);
            acc[kt][r] = p;
            s[r] += p;
        }
    }
#pragma unroll
    for (int r = 0; r < 4; ++r) {
#pragma unroll
        for (int off = 1; off < 16; off <<= 1) s[r] += __shfl_xor(s[r], off);
    }
    if ((lane & 15) == 0) {
#pragma unroll
        for (int r = 0; r < 4; ++r) red[128 + w * 16 + (lane >> 4) * 4 + r] = s[r];
    }
    __syncthreads();

    float rinv[4];
#pragma unroll
    for (int r = 0; r < 4; ++r) {
        const int q = (lane >> 4) * 4 + r;
        float ss = red[128 + q];
#pragma unroll
        for (int ww = 1; ww < 8; ++ww) ss += red[128 + ww * 16 + q];
        rinv[r] = 1.f / ss;
    }
    __syncthreads();

    float* attn_base = attn_out + ((size_t)bh * SEQ + q0) * SEQ;
    char* Pb = (char*)P_lds;
#pragma unroll
    for (int kt = 0; kt < 16; ++kt) {
#pragma unroll
        for (int r = 0; r < 4; ++r) {
            const int q = (lane >> 4) * 4 + r;
            const int k = w * 256 + kt * 16 + (lane & 15);
            const float p = acc[kt][r] * rinv[r];
            const int byte_in_row = (k * 2) ^ ((q & 7) << 4);
            *(ushort*)(Pb + q * 4096 + byte_in_row) = f2b(p);
            __builtin_nontemporal_store(p, &attn_base[(size_t)q * SEQ + k]);
        }
    }
    __syncthreads();

    f32x4 ctx[4];
#pragma unroll
    for (int ni = 0; ni < 4; ++ni) ctx[ni] = (f32x4){0.f, 0.f, 0.f, 0.f};

    const ushort* Vtp = Vt + (size_t)bh * DEPTH * SEQ;
#pragma unroll
    for (int s8 = 0; s8 < 8; ++s8) {
        const int kofs = w * 256 + s8 * 32 + (lane >> 4) * 8;
        const int row  = lane & 15;
        const bf16x8 af = *(const bf16x8*)(Pb + row * 4096 + ((kofs * 2) ^ ((row & 7) << 4)));
#pragma unroll
        for (int ni = 0; ni < 4; ++ni) {
            const bf16x8 bfr = *(const bf16x8*)&Vtp[(size_t)(ni * 16 + (lane & 15)) * SEQ + kofs];
            ctx[ni] = __builtin_amdgcn_mfma_f32_16x16x32_bf16(af, bfr, ctx[ni], 0, 0, 0);
        }
    }
    __syncthreads();

    float* part = (float*)P_lds;
#pragma unroll
    for (int ni = 0; ni < 4; ++ni) {
#pragma unroll
        for (int r = 0; r < 4; ++r) {
            part[(w * 16 + (lane >> 4) * 4 + r) * 64 + ni * 16 + (lane & 15)] = ctx[ni][r];
        }
    }
    __syncthreads();

#pragma unroll
    for (int idx = t; idx < 1024; idx += 512) {
        const int q = idx >> 6, d = idx & 63;
        float ssum = 0.f;
#pragma unroll
        for (int ww = 0; ww < 8; ++ww) ssum += part[ww * 1024 + idx];
        Ctx[(size_t)(b * SEQ + q0 + q) * DM + h * DEPTH + d] = f2b(ssum);
    }
}

extern "C" void kernel_launch(void* const* d_in, const int* in_sizes, int n_in,
                              void* d_out, int out_size, void* d_ws, size_t ws_size,
                              hipStream_t stream) {
    const float* x  = (const float*)d_in[0];
    const float* wq = (const float*)d_in[1];
    const float* bq = (const float*)d_in[2];
    const float* wk = (const float*)d_in[3];
    const float* bk = (const float*)d_in[4];
    const float* wv = (const float*)d_in[5];
    const float* bv = (const float*)d_in[6];
    const float* wo = (const float*)d_in[7];
    const float* bo = (const float*)d_in[8];

    float* out  = (float*)d_out;                          // [2,2048,1024]
    float* attn = out + (size_t)MROWS * DM;               // [2,16,2048,2048] fp32

    ushort* ws  = (ushort*)d_ws;
    ushort* xb  = ws;                        // 4096x1024 bf16
    ushort* wqt = xb + (size_t)MROWS * DM;   // [wqt|wkt|wvt|wot] contiguous, each 1024x1024
    ushort* wot = wqt + (size_t)3 * DM * DM;
    ushort* Qh  = wot + (size_t)DM * DM;     // [Qh|Kh|Vh] contiguous, each 4096x1024 bf16
    ushort* Kh  = Qh + (size_t)MROWS * DM;
    ushort* Vh  = Kh + (size_t)MROWS * DM;
    ushort* cxb = Vh + (size_t)MROWS * DM;
    ushort* Vt  = cxb + (size_t)MROWS * DM;  // [32][64][2048] bf16

    convert_f32_bf16<<<dim3(MROWS * DM / 4 / 256), 256, 0, stream>>>(x, xb, MROWS * DM / 4);
    transpose_convert4<<<dim3(DM / 32, DM / 32, 4), 256, 0, stream>>>(wq, wk, wv, wo, wqt);

    gemm_qkv_mfma<<<dim3(3 * DM / 128, MROWS / 128), 256, 0, stream>>>(xb, wqt, bq, bk, bv, Qh);

    transpose_v<<<dim3(BATCH * NH, SEQ / 64), 256, 0, stream>>>(Vh, Vt);

    attn_fused_kernel<<<dim3(SEQ / 16, BATCH * NH), 512, 0, stream>>>(Qh, Kh, Vt, attn, cxb);

    gemm_mfma_f32<<<dim3(DM / 128, MROWS / 128), 256, 0, stream>>>(cxb, wot, bo, out);
}

// Round 8
// 338.160 us; speedup vs baseline: 10.8359x; 1.0746x over previous
//
#include <hip/hip_runtime.h>
#include <hip/hip_bf16.h>

#define SEQ 2048
#define BATCH 2
#define NH 16
#define DM 1024
#define DEPTH 64
#define MROWS (BATCH * SEQ)   // 4096

typedef __attribute__((ext_vector_type(8))) short bf16x8;
typedef __attribute__((ext_vector_type(4))) float f32x4;

__device__ __forceinline__ float b2f(ushort u) {
    union { uint i; float f; } v; v.i = ((uint)u) << 16; return v.f;
}
__device__ __forceinline__ ushort f2b(float f) {
    __hip_bfloat16 h = __float2bfloat16(f);
    return *reinterpret_cast<ushort*>(&h);
}

__device__ __forceinline__ void gload_lds16(const void* g, void* l) {
    __builtin_amdgcn_global_load_lds((const __attribute__((address_space(1))) void*)g,
                                     (__attribute__((address_space(3))) void*)l, 16, 0, 0);
}

// ---------------- fp32 -> bf16 elementwise ----------------
__global__ __launch_bounds__(256) void convert_f32_bf16(const float* __restrict__ in,
                                                        ushort* __restrict__ outp, int n4) {
    int i = blockIdx.x * 256 + threadIdx.x;
    if (i < n4) {
        const float4 v = ((const float4*)in)[i];
        ushort4 o;
        o.x = f2b(v.x); o.y = f2b(v.y); o.z = f2b(v.z); o.w = f2b(v.w);
        ((ushort4*)outp)[i] = o;
    }
}

// ---------------- 4x fused: fp32 W[K][N] -> bf16 Wt[N][K], z selects weight ----------------
__global__ __launch_bounds__(256) void transpose_convert4(const float* __restrict__ w0,
                                                          const float* __restrict__ w1,
                                                          const float* __restrict__ w2,
                                                          const float* __restrict__ w3,
                                                          ushort* __restrict__ WtBase) {
    __shared__ float tile[32][33];
    const int z = blockIdx.z;
    const float* W = (z == 0) ? w0 : (z == 1) ? w1 : (z == 2) ? w2 : w3;
    ushort* Wt = WtBase + (size_t)z * DM * DM;
    const int bx = blockIdx.x * 32;  // n base
    const int by = blockIdx.y * 32;  // k base
    const int tx = threadIdx.x & 31, ty = threadIdx.x >> 5;
#pragma unroll
    for (int i = 0; i < 32; i += 8)
        tile[ty + i][tx] = W[(size_t)(by + ty + i) * DM + bx + tx];
    __syncthreads();
#pragma unroll
    for (int i = 0; i < 32; i += 8)
        Wt[(size_t)(bx + ty + i) * DM + by + tx] = f2b(tile[tx][ty + i]);
}

// ---------------- fused QKV GEMM: [4096,1024] @ [1024,3072] + bias -> bf16 ----------------
__global__ __launch_bounds__(256) void gemm_qkv_mfma(const ushort* __restrict__ A,
                                                     const ushort* __restrict__ WtAll,
                                                     const float* __restrict__ bq,
                                                     const float* __restrict__ bk,
                                                     const float* __restrict__ bv,
                                                     ushort* __restrict__ OutBase) {
    __shared__ __align__(16) ushort As[128 * 32];
    __shared__ __align__(16) ushort Bs[128 * 32];

    const int t    = threadIdx.x;
    const int lane = t & 63;
    const int w    = t >> 6;
    const int wr   = w >> 1, wc = w & 1;
    const int row0 = blockIdx.y * 128;
    const int col0 = blockIdx.x * 128;           // 0..2944
    const int bank = col0 >> 10;                 // 0,1,2
    const float* bias = (bank == 0) ? bq : (bank == 1) ? bk : bv;
    const int ccol0 = col0 & 1023;
    ushort* Cout = OutBase + (size_t)bank * MROWS * DM;

    f32x4 acc[4][4];
#pragma unroll
    for (int mi = 0; mi < 4; ++mi)
#pragma unroll
        for (int ni = 0; ni < 4; ++ni) acc[mi][ni] = (f32x4){0.f, 0.f, 0.f, 0.f};

    const int sr = t >> 2;
    const int sc = (t & 3) * 8;

    for (int k0 = 0; k0 < DM; k0 += 32) {
        gload_lds16(&A[(size_t)(row0 + sr) * DM + k0 + sc],          &As[w * 512]);
        gload_lds16(&A[(size_t)(row0 + 64 + sr) * DM + k0 + sc],     &As[2048 + w * 512]);
        gload_lds16(&WtAll[(size_t)(col0 + sr) * DM + k0 + sc],      &Bs[w * 512]);
        gload_lds16(&WtAll[(size_t)(col0 + 64 + sr) * DM + k0 + sc], &Bs[2048 + w * 512]);
        __syncthreads();

        bf16x8 af[4], bfr[4];
#pragma unroll
        for (int mi = 0; mi < 4; ++mi)
            af[mi] = *(const bf16x8*)&As[(wr * 64 + mi * 16 + (lane & 15)) * 32 + (lane >> 4) * 8];
#pragma unroll
        for (int ni = 0; ni < 4; ++ni)
            bfr[ni] = *(const bf16x8*)&Bs[(wc * 64 + ni * 16 + (lane & 15)) * 32 + (lane >> 4) * 8];
#pragma unroll
        for (int mi = 0; mi < 4; ++mi)
#pragma unroll
            for (int ni = 0; ni < 4; ++ni)
                acc[mi][ni] = __builtin_amdgcn_mfma_f32_16x16x32_bf16(af[mi], bfr[ni], acc[mi][ni], 0, 0, 0);
        __syncthreads();
    }

    float bb[4];
#pragma unroll
    for (int ni = 0; ni < 4; ++ni) bb[ni] = bias[ccol0 + wc * 64 + ni * 16 + (lane & 15)];

#pragma unroll
    for (int mi = 0; mi < 4; ++mi) {
        const int row = row0 + wr * 64 + mi * 16 + (lane >> 4) * 4;
#pragma unroll
        for (int ni = 0; ni < 4; ++ni) {
            const int col = ccol0 + wc * 64 + ni * 16 + (lane & 15);
#pragma unroll
            for (int r = 0; r < 4; ++r)
                Cout[(size_t)(row + r) * DM + col] = f2b(acc[mi][ni][r] + bb[ni]);
        }
    }
}

// ---------------- bf16 MFMA GEMM: C = A @ Wt^T + bias, fp32 out ----------------
__global__ __launch_bounds__(256) void gemm_mfma_f32(const ushort* __restrict__ A,
                                                     const ushort* __restrict__ Wt,
                                                     const float* __restrict__ bias,
                                                     float* __restrict__ Cout) {
    __shared__ __align__(16) ushort As[128 * 32];
    __shared__ __align__(16) ushort Bs[128 * 32];

    const int t    = threadIdx.x;
    const int lane = t & 63;
    const int w    = t >> 6;
    const int wr   = w >> 1, wc = w & 1;
    const int row0 = blockIdx.y * 128;
    const int col0 = blockIdx.x * 128;

    f32x4 acc[4][4];
#pragma unroll
    for (int mi = 0; mi < 4; ++mi)
#pragma unroll
        for (int ni = 0; ni < 4; ++ni) acc[mi][ni] = (f32x4){0.f, 0.f, 0.f, 0.f};

    const int sr = t >> 2;
    const int sc = (t & 3) * 8;

    for (int k0 = 0; k0 < DM; k0 += 32) {
        gload_lds16(&A[(size_t)(row0 + sr) * DM + k0 + sc],       &As[w * 512]);
        gload_lds16(&A[(size_t)(row0 + 64 + sr) * DM + k0 + sc],  &As[2048 + w * 512]);
        gload_lds16(&Wt[(size_t)(col0 + sr) * DM + k0 + sc],      &Bs[w * 512]);
        gload_lds16(&Wt[(size_t)(col0 + 64 + sr) * DM + k0 + sc], &Bs[2048 + w * 512]);
        __syncthreads();

        bf16x8 af[4], bfr[4];
#pragma unroll
        for (int mi = 0; mi < 4; ++mi)
            af[mi] = *(const bf16x8*)&As[(wr * 64 + mi * 16 + (lane & 15)) * 32 + (lane >> 4) * 8];
#pragma unroll
        for (int ni = 0; ni < 4; ++ni)
            bfr[ni] = *(const bf16x8*)&Bs[(wc * 64 + ni * 16 + (lane & 15)) * 32 + (lane >> 4) * 8];
#pragma unroll
        for (int mi = 0; mi < 4; ++mi)
#pragma unroll
            for (int ni = 0; ni < 4; ++ni)
                acc[mi][ni] = __builtin_amdgcn_mfma_f32_16x16x32_bf16(af[mi], bfr[ni], acc[mi][ni], 0, 0, 0);
        __syncthreads();
    }

    float bb[4];
#pragma unroll
    for (int ni = 0; ni < 4; ++ni) bb[ni] = bias[col0 + wc * 64 + ni * 16 + (lane & 15)];

#pragma unroll
    for (int mi = 0; mi < 4; ++mi) {
        const int row = row0 + wr * 64 + mi * 16 + (lane >> 4) * 4;
#pragma unroll
        for (int ni = 0; ni < 4; ++ni) {
            const int col = col0 + wc * 64 + ni * 16 + (lane & 15);
#pragma unroll
            for (int r = 0; r < 4; ++r)
                Cout[(size_t)(row + r) * DM + col] = acc[mi][ni][r] + bb[ni];
        }
    }
}

// ---------------- V panel transpose: Vh[B,S,H*64] -> Vt[32][64 d][2048 k] bf16 ----------------
__global__ __launch_bounds__(256) void transpose_v(const ushort* __restrict__ Vh,
                                                   ushort* __restrict__ Vt) {
    __shared__ ushort tile[64][80];
    const int t  = threadIdx.x;
    const int bh = blockIdx.x;
    const int k0 = blockIdx.y * 64;
    const int b  = bh >> 4;
    const int h  = bh & 15;
    const size_t panel = (size_t)b * SEQ * DM + (size_t)h * DEPTH;

    {
        const int k = t >> 2, dc = (t & 3) * 16;
        const ushort* src = Vh + panel + (size_t)(k0 + k) * DM + dc;
        *(bf16x8*)&tile[k][dc]     = *(const bf16x8*)src;
        *(bf16x8*)&tile[k][dc + 8] = *(const bf16x8*)(src + 8);
    }
    __syncthreads();
    {
        const int d = t >> 2, kc = (t & 3) * 16;
        bf16x8 o0, o1;
#pragma unroll
        for (int j = 0; j < 8; ++j) o0[j] = tile[kc + j][d];
#pragma unroll
        for (int j = 0; j < 8; ++j) o1[j] = tile[kc + 8 + j][d];
        ushort* dst = Vt + ((size_t)bh * DEPTH + d) * SEQ + k0 + kc;
        *(bf16x8*)dst       = o0;
        *(bf16x8*)(dst + 8) = o1;
    }
}

// ---------------- fused attention (panel-major grid; coalesced LDS-staged attn write) ----------------
__global__ __launch_bounds__(512, 4) void attn_fused_kernel(const ushort* __restrict__ Qh,
                                                            const ushort* __restrict__ Kh,
                                                            const ushort* __restrict__ Vt,
                                                            float* __restrict__ attn_out,
                                                            ushort* __restrict__ Ctx) {
    __shared__ __align__(16) ushort P_lds[16 * 2048];   // 64 KB
    float* red = (float*)P_lds;

    const int t    = threadIdx.x;
    const int lane = t & 63;
    const int w    = t >> 6;          // 0..7
    const int qt   = blockIdx.x;      // 0..127 fast axis
    const int bh   = blockIdx.y;      // 0..31  slow axis -> panel-major dispatch
    const int b    = bh >> 4;
    const int h    = bh & 15;
    const int q0   = qt * 16;

    const size_t panel = (size_t)b * SEQ * DM + (size_t)h * DEPTH;

    const ushort* Qrow = Qh + panel + (size_t)(q0 + (lane & 15)) * DM + (lane >> 4) * 8;
    const bf16x8 qf0 = *(const bf16x8*)Qrow;
    const bf16x8 qf1 = *(const bf16x8*)(Qrow + 32);

    f32x4 acc[16];
#pragma unroll
    for (int kt = 0; kt < 16; ++kt) acc[kt] = (f32x4){0.f, 0.f, 0.f, 0.f};

    const ushort* Kbase = Kh + panel + (size_t)(w * 256) * DM + (lane >> 4) * 8;
#pragma unroll
    for (int kt = 0; kt < 16; ++kt) {
        const ushort* Kr = Kbase + (size_t)(kt * 16 + (lane & 15)) * DM;
        const bf16x8 kf0 = *(const bf16x8*)Kr;
        const bf16x8 kf1 = *(const bf16x8*)(Kr + 32);
        acc[kt] = __builtin_amdgcn_mfma_f32_16x16x32_bf16(qf0, kf0, acc[kt], 0, 0, 0);
        acc[kt] = __builtin_amdgcn_mfma_f32_16x16x32_bf16(qf1, kf1, acc[kt], 0, 0, 0);
    }

#pragma unroll
    for (int kt = 0; kt < 16; ++kt) {
        acc[kt][0] *= 0.125f; acc[kt][1] *= 0.125f;
        acc[kt][2] *= 0.125f; acc[kt][3] *= 0.125f;
    }

    float m[4];
#pragma unroll
    for (int r = 0; r < 4; ++r) {
        float mm = acc[0][r];
#pragma unroll
        for (int kt = 1; kt < 16; ++kt) mm = fmaxf(mm, acc[kt][r]);
#pragma unroll
        for (int off = 1; off < 16; off <<= 1) mm = fmaxf(mm, __shfl_xor(mm, off));
        m[r] = mm;
    }
    if ((lane & 15) == 0) {
#pragma unroll
        for (int r = 0; r < 4; ++r) red[w * 16 + (lane >> 4) * 4 + r] = m[r];
    }
    __syncthreads();

    float mx[4];
#pragma unroll
    for (int r = 0; r < 4; ++r) {
        const int q = (lane >> 4) * 4 + r;
        float mm = red[q];
#pragma unroll
        for (int ww = 1; ww < 8; ++ww) mm = fmaxf(mm, red[ww * 16 + q]);
        mx[r] = mm;
    }

    float s[4] = {0.f, 0.f, 0.f, 0.f};
#pragma unroll
    for (int kt = 0; kt < 16; ++kt) {
#pragma unroll
        for (int r = 0; r < 4; ++r) {
            const float p = __expf(acc[kt][r] - mx[r]);
            acc[kt][r] = p;
            s[r] += p;
        }
    }
#pragma unroll
    for (int r = 0; r < 4; ++r) {
#pragma unroll
        for (int off = 1; off < 16; off <<= 1) s[r] += __shfl_xor(s[r], off);
    }
    if ((lane & 15) == 0) {
#pragma unroll
        for (int r = 0; r < 4; ++r) red[128 + w * 16 + (lane >> 4) * 4 + r] = s[r];
    }
    __syncthreads();

    float rinv[4];
#pragma unroll
    for (int r = 0; r < 4; ++r) {
        const int q = (lane >> 4) * 4 + r;
        float ss = red[128 + q];
#pragma unroll
        for (int ww = 1; ww < 8; ++ww) ss += red[128 + ww * 16 + q];
        rinv[r] = 1.f / ss;
    }
    __syncthreads();   // red overlay dead -> P_lds writable

    // ---- phase 3: normalized P -> LDS only (bf16, swizzled)
    char* Pb = (char*)P_lds;
#pragma unroll
    for (int kt = 0; kt < 16; ++kt) {
#pragma unroll
        for (int r = 0; r < 4; ++r) {
            const int q = (lane >> 4) * 4 + r;
            const int k = w * 256 + kt * 16 + (lane & 15);
            const int byte_in_row = (k * 2) ^ ((q & 7) << 4);
            *(ushort*)(Pb + q * 4096 + byte_in_row) = f2b(acc[kt][r] * rinv[r]);
        }
    }
    __syncthreads();

    // ---- phase 3.5: coalesced attn write from LDS. Iteration it = q-row; thread t covers
    // k = t*4..t*4+3 -> per wave-inst 64 lanes x 16B = 1KB contiguous, nontemporal.
    float* attn_base = attn_out + ((size_t)bh * SEQ + q0) * SEQ;
#pragma unroll
    for (int it = 0; it < 16; ++it) {
        const int byte_in_row = (t * 8) ^ ((it & 7) << 4);
        const ushort4 p4 = *(const ushort4*)(Pb + it * 4096 + byte_in_row);
        f32x4 o;
        o[0] = b2f(p4.x); o[1] = b2f(p4.y); o[2] = b2f(p4.z); o[3] = b2f(p4.w);
        __builtin_nontemporal_store(o, (f32x4*)&attn_base[(size_t)it * SEQ + t * 4]);
    }
    // no barrier needed: phase 4 also only READS P_lds

    // ---- phase 4: PV. Wave w: ctx_partial[16 q][64 d] over its 256 keys.
    f32x4 ctx[4];
#pragma unroll
    for (int ni = 0; ni < 4; ++ni) ctx[ni] = (f32x4){0.f, 0.f, 0.f, 0.f};

    const ushort* Vtp = Vt + (size_t)bh * DEPTH * SEQ;
#pragma unroll
    for (int s8 = 0; s8 < 8; ++s8) {
        const int kofs = w * 256 + s8 * 32 + (lane >> 4) * 8;
        const int row  = lane & 15;
        const bf16x8 af = *(const bf16x8*)(Pb + row * 4096 + ((kofs * 2) ^ ((row & 7) << 4)));
#pragma unroll
        for (int ni = 0; ni < 4; ++ni) {
            const bf16x8 bfr = *(const bf16x8*)&Vtp[(size_t)(ni * 16 + (lane & 15)) * SEQ + kofs];
            ctx[ni] = __builtin_amdgcn_mfma_f32_16x16x32_bf16(af, bfr, ctx[ni], 0, 0, 0);
        }
    }
    __syncthreads();   // all P_lds reads done; reuse as f32 partials [8][16][64]

    float* part = (float*)P_lds;
#pragma unroll
    for (int ni = 0; ni < 4; ++ni) {
#pragma unroll
        for (int r = 0; r < 4; ++r) {
            part[(w * 16 + (lane >> 4) * 4 + r) * 64 + ni * 16 + (lane & 15)] = ctx[ni][r];
        }
    }
    __syncthreads();

#pragma unroll
    for (int idx = t; idx < 1024; idx += 512) {
        const int q = idx >> 6, d = idx & 63;
        float ssum = 0.f;
#pragma unroll
        for (int ww = 0; ww < 8; ++ww) ssum += part[ww * 1024 + idx];
        Ctx[(size_t)(b * SEQ + q0 + q) * DM + h * DEPTH + d] = f2b(ssum);
    }
}

extern "C" void kernel_launch(void* const* d_in, const int* in_sizes, int n_in,
                              void* d_out, int out_size, void* d_ws, size_t ws_size,
                              hipStream_t stream) {
    const float* x  = (const float*)d_in[0];
    const float* wq = (const float*)d_in[1];
    const float* bq = (const float*)d_in[2];
    const float* wk = (const float*)d_in[3];
    const float* bk = (const float*)d_in[4];
    const float* wv = (const float*)d_in[5];
    const float* bv = (const float*)d_in[6];
    const float* wo = (const float*)d_in[7];
    const float* bo = (const float*)d_in[8];

    float* out  = (float*)d_out;                          // [2,2048,1024]
    float* attn = out + (size_t)MROWS * DM;               // [2,16,2048,2048] fp32

    ushort* ws  = (ushort*)d_ws;
    ushort* xb  = ws;                        // 4096x1024 bf16
    ushort* wqt = xb + (size_t)MROWS * DM;   // [wqt|wkt|wvt|wot] contiguous, each 1024x1024
    ushort* wot = wqt + (size_t)3 * DM * DM;
    ushort* Qh  = wot + (size_t)DM * DM;     // [Qh|Kh|Vh] contiguous, each 4096x1024 bf16
    ushort* Kh  = Qh + (size_t)MROWS * DM;
    ushort* Vh  = Kh + (size_t)MROWS * DM;
    ushort* cxb = Vh + (size_t)MROWS * DM;
    ushort* Vt  = cxb + (size_t)MROWS * DM;  // [32][64][2048] bf16

    convert_f32_bf16<<<dim3(MROWS * DM / 4 / 256), 256, 0, stream>>>(x, xb, MROWS * DM / 4);
    transpose_convert4<<<dim3(DM / 32, DM / 32, 4), 256, 0, stream>>>(wq, wk, wv, wo, wqt);

    gemm_qkv_mfma<<<dim3(3 * DM / 128, MROWS / 128), 256, 0, stream>>>(xb, wqt, bq, bk, bv, Qh);

    transpose_v<<<dim3(BATCH * NH, SEQ / 64), 256, 0, stream>>>(Vh, Vt);

    attn_fused_kernel<<<dim3(SEQ / 16, BATCH * NH), 512, 0, stream>>>(Qh, Kh, Vt, attn, cxb);

    gemm_mfma_f32<<<dim3(DM / 128, MROWS / 128), 256, 0, stream>>>(cxb, wot, bo, out);
}